// Round 3
// baseline (273.543 us; speedup 1.0000x reference)
//
#include <hip/hip_runtime.h>
#include <stdint.h>

typedef unsigned short u16;
typedef __bf16 bf16;
typedef bf16 bf16x8 __attribute__((ext_vector_type(8)));
typedef float f32x4 __attribute__((ext_vector_type(4)));
typedef uint32_t u32x4 __attribute__((ext_vector_type(4)));

// ---- constants: B=4, S=4096, D_IN=768, D_OUT=128 ----
#define S_LEN 4096
#define D_IN 768
#define D_OUT 128
#define NB 4
#define M_TOTAL (NB * S_LEN) // 16384
#define NW 4                 // waves per attention block (KV-split factor)

static __device__ __forceinline__ u16 f2bf(float f) {
    union { float f; uint32_t u; } c; c.f = f;
    return (u16)((c.u + 0x7FFFu + ((c.u >> 16) & 1u)) >> 16);
}

static __device__ __forceinline__ bf16x8 ld8(const u16* p) {
    union { u32x4 v; bf16x8 b; } c;
    c.v = *reinterpret_cast<const u32x4*>(p);
    return c.b;
}

static __device__ __forceinline__ f32x4 mfma16(bf16x8 a, bf16x8 b, f32x4 c) {
    return __builtin_amdgcn_mfma_f32_16x16x32_bf16(a, b, c, 0, 0, 0);
}

// DPP-based 16-lane butterfly reduce (stays within each 16-lane row group).
template <int CTRL>
static __device__ __forceinline__ float dpp_f(float v) {
    return __int_as_float(__builtin_amdgcn_update_dpp(0, __float_as_int(v), CTRL, 0xF, 0xF, true));
}
static __device__ __forceinline__ float red16_max(float x) {
    x = fmaxf(x, dpp_f<0xB1>(x));   // quad_perm [1,0,3,2] : lane^1
    x = fmaxf(x, dpp_f<0x4E>(x));   // quad_perm [2,3,0,1] : lane^2
    x = fmaxf(x, dpp_f<0x141>(x));  // row_half_mirror     : lane^7 (~^4 after quads equal)
    x = fmaxf(x, dpp_f<0x140>(x));  // row_mirror          : lane^15 (~^8)
    return x;
}
static __device__ __forceinline__ float red16_sum(float x) {
    x += dpp_f<0xB1>(x);
    x += dpp_f<0x4E>(x);
    x += dpp_f<0x141>(x);
    x += dpp_f<0x140>(x);
    return x;
}

// ---------------- Kernel 1: W -> W^T bf16 via LDS transpose ----------------
// grid 72 = 3 weights x 24 k-chunks of 32 rows; block 256.
__global__ __launch_bounds__(256) void wt_kernel(const float* __restrict__ Wq, const float* __restrict__ Wk,
                                                 const float* __restrict__ Wv, u16* __restrict__ Wt) {
    __shared__ u16 tl[128][40]; // [n][k], stride 40 u16 = 80 B (16B-aligned rows)
    const int w = blockIdx.x / 24;
    const int kc = (blockIdx.x % 24) * 32;
    const float* W = (w == 0) ? Wq : (w == 1) ? Wk : Wv;
#pragma unroll
    for (int p = 0; p < 4; ++p) {
        int kr = p * 8 + (threadIdx.x >> 5);
        int nc = (threadIdx.x & 31) * 4;
        float4 v = *reinterpret_cast<const float4*>(W + (size_t)(kc + kr) * D_OUT + nc);
        tl[nc + 0][kr] = f2bf(v.x); tl[nc + 1][kr] = f2bf(v.y);
        tl[nc + 2][kr] = f2bf(v.z); tl[nc + 3][kr] = f2bf(v.w);
    }
    __syncthreads();
    const int n = threadIdx.x >> 1, kh = (threadIdx.x & 1) * 16;
    u32x4* dst = reinterpret_cast<u32x4*>(Wt + (size_t)w * D_OUT * D_IN + (size_t)n * D_IN + kc + kh);
    const u32x4* src = reinterpret_cast<const u32x4*>(&tl[n][kh]);
    dst[0] = src[0];
    dst[1] = src[1];
}

// ---------------- Kernel 2: QKV projection GEMM ----------------
// grid(256, 3), block 256 (4 waves x 16 rows). Q (pre-scaled by 1/sqrt(d)),K row-major bf16;
// V stored transposed.
__global__ __launch_bounds__(256) void qkv_kernel(const float* __restrict__ x, const u16* __restrict__ Wt,
                                                  u16* __restrict__ Qb, u16* __restrict__ Kb,
                                                  u16* __restrict__ Vt) {
    const int wave = threadIdx.x >> 6, lane = threadIdx.x & 63;
    const int r = lane & 15, g = lane >> 4;
    const int m0 = blockIdx.x * 64 + wave * 16;
    const int y = blockIdx.y;
    const u16* wt = Wt + y * (D_OUT * D_IN);

    f32x4 acc[8];
#pragma unroll
    for (int f = 0; f < 8; ++f) acc[f] = f32x4{0.f, 0.f, 0.f, 0.f};

    const float* ap0 = x + (size_t)(m0 + r) * D_IN;
#pragma unroll 2
    for (int kk = 0; kk < D_IN / 32; ++kk) {
        const int kbase = kk * 32 + 8 * g;
        const float* ap = ap0 + kbase;
        float4 a0 = *reinterpret_cast<const float4*>(ap);
        float4 a1 = *reinterpret_cast<const float4*>(ap + 4);
        bf16x8 wf[8];
#pragma unroll
        for (int f = 0; f < 8; ++f) wf[f] = ld8(wt + (size_t)(f * 16 + r) * D_IN + kbase);
        union { u16 u[8]; bf16x8 b; } af;
        af.u[0] = f2bf(a0.x); af.u[1] = f2bf(a0.y); af.u[2] = f2bf(a0.z); af.u[3] = f2bf(a0.w);
        af.u[4] = f2bf(a1.x); af.u[5] = f2bf(a1.y); af.u[6] = f2bf(a1.z); af.u[7] = f2bf(a1.w);
#pragma unroll
        for (int f = 0; f < 8; ++f) acc[f] = mfma16(af.b, wf[f], acc[f]);
    }

    if (y == 0) {
        const float sc = 0.08838834764831845f; // 1/sqrt(128) folded into Q
#pragma unroll
        for (int f = 0; f < 8; ++f)
#pragma unroll
            for (int i = 0; i < 4; ++i)
                Qb[(size_t)(m0 + 4 * g + i) * D_OUT + f * 16 + r] = f2bf(acc[f][i] * sc);
    } else if (y == 1) {
#pragma unroll
        for (int f = 0; f < 8; ++f)
#pragma unroll
            for (int i = 0; i < 4; ++i)
                Kb[(size_t)(m0 + 4 * g + i) * D_OUT + f * 16 + r] = f2bf(acc[f][i]);
    } else {
        // V^T: Vt[b][d][pos], b = mrow>>12, pos = mrow&4095
#pragma unroll
        for (int f = 0; f < 8; ++f)
#pragma unroll
            for (int i = 0; i < 4; ++i) {
                int mrow = m0 + 4 * g + i;
                Vt[((size_t)((mrow >> 12) * D_OUT + f * 16 + r)) * S_LEN + (mrow & 4095)] = f2bf(acc[f][i]);
            }
    }
}

// ---------------- Kernel 3: causal flash attention ----------------
// grid(256, 4), block 256 = 4 waves. One 16-row Q tile per BLOCK; waves interleave
// KV tiles stride-NW with private (m,l,O~); LDS combine at the end.
// tile direction alternates with batch parity so each CU's total work is constant.
__global__ __launch_bounds__(256) void attn_kernel(const u16* __restrict__ Qb, const u16* __restrict__ Kb,
                                                   const u16* __restrict__ Vt, float* __restrict__ out) {
    __shared__ u16 plds[NW][16 * 72]; // per-wave P transpose buffer (row stride 72 bf16)
    __shared__ float m_s[NW][16], l_s[NW][16];
    __shared__ float o_acc[16][128];

    const int wave = threadIdx.x >> 6, lane = threadIdx.x & 63;
    const int r = lane & 15, g = lane >> 4;
    const int b = blockIdx.y;
    const int tile = (b & 1) ? (int)blockIdx.x : 255 - (int)blockIdx.x;
    const int q0 = tile << 4;

    // Q fragments (A layout): row = q0 + (l&15), k = kk*32 + 8*(l>>4) + j
    const u16* Qp = Qb + ((size_t)(b * S_LEN + q0 + r)) * D_OUT + 8 * g;
    bf16x8 qf[4];
#pragma unroll
    for (int kk = 0; kk < 4; ++kk) qf[kk] = ld8(Qp + kk * 32);

    f32x4 o[8];
#pragma unroll
    for (int f = 0; f < 8; ++f) o[f] = f32x4{0.f, 0.f, 0.f, 0.f};
    float m_[4], l_[4];
#pragma unroll
    for (int i = 0; i < 4; ++i) { m_[i] = -1e30f; l_[i] = 0.f; }

    const u16* Kp = Kb + (size_t)b * S_LEN * D_OUT;
    const u16* Vp = Vt + (size_t)b * D_OUT * S_LEN;
    const int kend = q0 + 16;
    const float LOG2E = 1.4426950408889634f;

    for (int k0 = wave * 64; k0 < kend; k0 += NW * 64) {
        // ---- prefetch all 16 K fragments into registers, then MFMA ----
        const u16* kp0 = Kp + (size_t)(k0 + r) * D_OUT + 8 * g;
        bf16x8 ka[8], kb[8];
#pragma unroll
        for (int f = 0; f < 4; ++f) {
            ka[f] = ld8(kp0 + (size_t)f * 16 * D_OUT);             // kk=0
            ka[4 + f] = ld8(kp0 + (size_t)f * 16 * D_OUT + 32);    // kk=1
        }
#pragma unroll
        for (int f = 0; f < 4; ++f) {
            kb[f] = ld8(kp0 + (size_t)f * 16 * D_OUT + 64);        // kk=2
            kb[4 + f] = ld8(kp0 + (size_t)f * 16 * D_OUT + 96);    // kk=3
        }
        f32x4 s[4];
#pragma unroll
        for (int f = 0; f < 4; ++f) s[f] = f32x4{0.f, 0.f, 0.f, 0.f};
#pragma unroll
        for (int f = 0; f < 4; ++f) {
            s[f] = mfma16(qf[0], ka[f], s[f]);
            s[f] = mfma16(qf[1], ka[4 + f], s[f]);
        }
        // ---- issue first half of V loads (latency hides under softmax) ----
        const u16* vp0 = Vp + (size_t)r * S_LEN + k0 + 8 * g;
        bf16x8 va[8];
#pragma unroll
        for (int f = 0; f < 8; ++f) va[f] = ld8(vp0 + (size_t)f * 16 * S_LEN);
#pragma unroll
        for (int f = 0; f < 4; ++f) {
            s[f] = mfma16(qf[2], kb[f], s[f]);
            s[f] = mfma16(qf[3], kb[4 + f], s[f]);
        }

        // ---- causal mask (last tile only) + row max ----
        float pm[4] = {-1e30f, -1e30f, -1e30f, -1e30f};
        const bool last = (k0 + 64 >= kend);
        if (last) {
#pragma unroll
            for (int f = 0; f < 4; ++f)
#pragma unroll
                for (int i = 0; i < 4; ++i) {
                    float v = s[f][i];
                    int kc = k0 + f * 16 + r;
                    int qr = q0 + 4 * g + i;
                    if (kc > qr) v = -1e30f;
                    s[f][i] = v;
                    pm[i] = fmaxf(pm[i], v);
                }
        } else {
#pragma unroll
            for (int f = 0; f < 4; ++f)
#pragma unroll
                for (int i = 0; i < 4; ++i) pm[i] = fmaxf(pm[i], s[f][i]);
        }
#pragma unroll
        for (int i = 0; i < 4; ++i) pm[i] = red16_max(pm[i]);

        // ---- online softmax update ----
        float al[4], rs[4];
#pragma unroll
        for (int i = 0; i < 4; ++i) {
            float mn = fmaxf(m_[i], pm[i]);
            al[i] = exp2f((m_[i] - mn) * LOG2E);
            m_[i] = mn;
            rs[i] = 0.f;
        }
#pragma unroll
        for (int f = 0; f < 4; ++f)
#pragma unroll
            for (int i = 0; i < 4; ++i) {
                float p = exp2f((s[f][i] - m_[i]) * LOG2E);
                s[f][i] = p;
                rs[i] += p;
            }
#pragma unroll
        for (int i = 0; i < 4; ++i) {
            rs[i] = red16_sum(rs[i]);
            l_[i] = l_[i] * al[i] + rs[i];
        }
#pragma unroll
        for (int f = 0; f < 8; ++f)
#pragma unroll
            for (int i = 0; i < 4; ++i) o[f][i] *= al[i];

        // ---- P: D layout -> A layout through this wave's LDS buffer ----
#pragma unroll
        for (int f = 0; f < 4; ++f)
#pragma unroll
            for (int i = 0; i < 4; ++i)
                plds[wave][(4 * g + i) * 72 + f * 16 + r] = f2bf(s[f][i]);
        asm volatile("s_waitcnt lgkmcnt(0)" ::: "memory");
        __builtin_amdgcn_sched_barrier(0);

        // ---- second half of V loads, then O += P V ----
        bf16x8 vb[8];
#pragma unroll
        for (int f = 0; f < 8; ++f) vb[f] = ld8(vp0 + (size_t)f * 16 * S_LEN + 32);

        bf16x8 pf0 = ld8(&plds[wave][r * 72 + 8 * g]);
#pragma unroll
        for (int f = 0; f < 8; ++f) o[f] = mfma16(pf0, va[f], o[f]);
        bf16x8 pf1 = ld8(&plds[wave][r * 72 + 32 + 8 * g]);
#pragma unroll
        for (int f = 0; f < 8; ++f) o[f] = mfma16(pf1, vb[f], o[f]);
    }

    // ---- cross-wave combine ----
    if (r == 0) {
#pragma unroll
        for (int i = 0; i < 4; ++i) { m_s[wave][4 * g + i] = m_[i]; l_s[wave][4 * g + i] = l_[i]; }
    }
    __syncthreads();

    float scale[4];
#pragma unroll
    for (int i = 0; i < 4; ++i) {
        int row = 4 * g + i;
        float mm = fmaxf(fmaxf(m_s[0][row], m_s[1][row]), fmaxf(m_s[2][row], m_s[3][row]));
        scale[i] = exp2f((m_[i] - mm) * LOG2E); // 0 for no-work waves (m_=-1e30)
    }
    for (int t = threadIdx.x; t < 16 * 128; t += 256) ((float*)o_acc)[t] = 0.f;
    __syncthreads();

    for (int w = 0; w < NW; ++w) {
        if (wave == w) {
#pragma unroll
            for (int f = 0; f < 8; ++f)
#pragma unroll
                for (int i = 0; i < 4; ++i)
                    o_acc[4 * g + i][f * 16 + r] += o[f][i] * scale[i];
        }
        __syncthreads();
    }

    // ---- normalize + coalesced write: thread t -> row t>>4, cols (t&15)*8.. ----
    {
        const int row = threadIdx.x >> 4, c0 = (threadIdx.x & 15) * 8;
        float mm = fmaxf(fmaxf(m_s[0][row], m_s[1][row]), fmaxf(m_s[2][row], m_s[3][row]));
        float ls = 0.f;
#pragma unroll
        for (int w = 0; w < NW; ++w) ls += l_s[w][row] * exp2f((m_s[w][row] - mm) * LOG2E);
        const float invl = 1.0f / ls;
        float* op = out + ((size_t)(b * S_LEN + q0 + row)) * D_OUT + c0;
        float4 v0, v1;
        v0.x = o_acc[row][c0 + 0] * invl; v0.y = o_acc[row][c0 + 1] * invl;
        v0.z = o_acc[row][c0 + 2] * invl; v0.w = o_acc[row][c0 + 3] * invl;
        v1.x = o_acc[row][c0 + 4] * invl; v1.y = o_acc[row][c0 + 5] * invl;
        v1.z = o_acc[row][c0 + 6] * invl; v1.w = o_acc[row][c0 + 7] * invl;
        *reinterpret_cast<float4*>(op) = v0;
        *reinterpret_cast<float4*>(op + 4) = v1;
    }
}

extern "C" void kernel_launch(void* const* d_in, const int* in_sizes, int n_in,
                              void* d_out, int out_size, void* d_ws, size_t ws_size,
                              hipStream_t stream) {
    const float* x  = (const float*)d_in[0];
    const float* Wq = (const float*)d_in[1];
    const float* Wk = (const float*)d_in[2];
    const float* Wv = (const float*)d_in[3];
    float* out = (float*)d_out;

    // workspace layout (bf16 ushorts): Q | K | V^T | W^T  = ~12.6 MiB
    u16* Qb = (u16*)d_ws;
    u16* Kb = Qb + (size_t)M_TOTAL * D_OUT;
    u16* Vt = Kb + (size_t)M_TOTAL * D_OUT;
    u16* Wt = Vt + (size_t)M_TOTAL * D_OUT;

    wt_kernel<<<72, 256, 0, stream>>>(Wq, Wk, Wv, Wt);
    qkv_kernel<<<dim3(M_TOTAL / 64, 3), 256, 0, stream>>>(x, Wt, Qb, Kb, Vt);
    attn_kernel<<<dim3(S_LEN / 16, NB), 256, 0, stream>>>(Qb, Kb, Vt, out);
}

// Round 4
// 229.485 us; speedup vs baseline: 1.1920x; 1.1920x over previous
//
#include <hip/hip_runtime.h>
#include <stdint.h>

typedef unsigned short u16;
typedef __bf16 bf16;
typedef bf16 bf16x8 __attribute__((ext_vector_type(8)));
typedef float f32x4 __attribute__((ext_vector_type(4)));
typedef uint32_t u32x4 __attribute__((ext_vector_type(4)));

// ---- constants: B=4, S=4096, D_IN=768, D_OUT=128 ----
#define S_LEN 4096
#define D_IN 768
#define D_OUT 128
#define NB 4
#define M_TOTAL (NB * S_LEN) // 16384

static __device__ __forceinline__ u16 f2bf(float f) {
    union { float f; uint32_t u; } c; c.f = f;
    return (u16)((c.u + 0x7FFFu + ((c.u >> 16) & 1u)) >> 16);
}

static __device__ __forceinline__ bf16x8 ld8(const u16* p) {
    union { u32x4 v; bf16x8 b; } c;
    c.v = *reinterpret_cast<const u32x4*>(p);
    return c.b;
}

static __device__ __forceinline__ f32x4 mfma16(bf16x8 a, bf16x8 b, f32x4 c) {
    return __builtin_amdgcn_mfma_f32_16x16x32_bf16(a, b, c, 0, 0, 0);
}

// async global->LDS, 16B per lane; dest = uniform base + lane*16 (linear)
static __device__ __forceinline__ void gload16(const void* g, void* l) {
    __builtin_amdgcn_global_load_lds((const __attribute__((address_space(1))) uint32_t*)g,
                                     (__attribute__((address_space(3))) uint32_t*)l, 16, 0, 0);
}

// DPP-based 16-lane butterfly reduce (stays within each 16-lane row group).
template <int CTRL>
static __device__ __forceinline__ float dpp_f(float v) {
    return __int_as_float(__builtin_amdgcn_update_dpp(0, __float_as_int(v), CTRL, 0xF, 0xF, true));
}
static __device__ __forceinline__ float red16_max(float x) {
    x = fmaxf(x, dpp_f<0xB1>(x));   // quad_perm lane^1
    x = fmaxf(x, dpp_f<0x4E>(x));   // quad_perm lane^2
    x = fmaxf(x, dpp_f<0x141>(x));  // row_half_mirror
    x = fmaxf(x, dpp_f<0x140>(x));  // row_mirror
    return x;
}
static __device__ __forceinline__ float red16_sum(float x) {
    x += dpp_f<0xB1>(x);
    x += dpp_f<0x4E>(x);
    x += dpp_f<0x141>(x);
    x += dpp_f<0x140>(x);
    return x;
}

// ---------------- Kernel 1: W -> W^T bf16 via LDS transpose ----------------
__global__ __launch_bounds__(256) void wt_kernel(const float* __restrict__ Wq, const float* __restrict__ Wk,
                                                 const float* __restrict__ Wv, u16* __restrict__ Wt) {
    __shared__ u16 tl[128][40];
    const int w = blockIdx.x / 24;
    const int kc = (blockIdx.x % 24) * 32;
    const float* W = (w == 0) ? Wq : (w == 1) ? Wk : Wv;
#pragma unroll
    for (int p = 0; p < 4; ++p) {
        int kr = p * 8 + (threadIdx.x >> 5);
        int nc = (threadIdx.x & 31) * 4;
        float4 v = *reinterpret_cast<const float4*>(W + (size_t)(kc + kr) * D_OUT + nc);
        tl[nc + 0][kr] = f2bf(v.x); tl[nc + 1][kr] = f2bf(v.y);
        tl[nc + 2][kr] = f2bf(v.z); tl[nc + 3][kr] = f2bf(v.w);
    }
    __syncthreads();
    const int n = threadIdx.x >> 1, kh = (threadIdx.x & 1) * 16;
    u32x4* dst = reinterpret_cast<u32x4*>(Wt + (size_t)w * D_OUT * D_IN + (size_t)n * D_IN + kc + kh);
    const u32x4* src = reinterpret_cast<const u32x4*>(&tl[n][kh]);
    dst[0] = src[0];
    dst[1] = src[1];
}

// ---------------- Kernel 2: fused QKV projection ----------------
// grid 256, block 256 (4 waves x 16 rows). One pass over x computes Q,K,V.
// Q pre-scaled by log2(e)/sqrt(128). W-slab + x-slab staged in LDS, 2-phase pipeline.
__global__ __launch_bounds__(256) void qkv_kernel(const float* __restrict__ x, const u16* __restrict__ Wt,
                                                  u16* __restrict__ Qb, u16* __restrict__ Kb,
                                                  u16* __restrict__ Vt) {
    __shared__ __align__(16) u16 wslab[2][384 * 32]; // [y*128+n][32k], 64B rows, chunk^=(row&3)
    __shared__ __align__(16) float xslab[64 * 32];   // [row][32k] f32, 128B rows, chunk^=(row&7)
    const int wave = threadIdx.x >> 6, lane = threadIdx.x & 63;
    const int r = lane & 15, g = lane >> 4;
    const int m0 = blockIdx.x * 64;

    f32x4 acc[3][8];
#pragma unroll
    for (int y = 0; y < 3; ++y)
#pragma unroll
        for (int f = 0; f < 8; ++f) acc[y][f] = f32x4{0.f, 0.f, 0.f, 0.f};

    const int wrow_l = lane >> 2, wch_l = lane & 3;
    const int xrow_l = lane >> 3, xch_l = lane & 7;

    auto stageW = [&](int bb, int kk) {
#pragma unroll
        for (int i = 0; i < 6; ++i) {
            int c = i * 4 + wave;                 // 0..23, 1KB chunks (16 rows)
            int row = c * 16 + wrow_l;
            const u16* src = Wt + (size_t)row * D_IN + kk * 32 + ((wch_l ^ (row & 3)) * 8);
            gload16(src, &wslab[bb][c * 512]);
        }
    };
    auto stageX = [&](int kk) {
#pragma unroll
        for (int i = 0; i < 2; ++i) {
            int c = i * 4 + wave;                 // 0..7, 1KB chunks (8 rows)
            int row = c * 8 + xrow_l;
            const float* src = x + (size_t)(m0 + row) * D_IN + kk * 32 + ((xch_l ^ (row & 7)) * 4);
            gload16(src, &xslab[c * 256]);
        }
    };

    stageW(0, 0);
    stageX(0);
    int buf = 0;
    const int arow = wave * 16 + r;
    for (int kk = 0; kk < 24; ++kk) {
        asm volatile("s_waitcnt vmcnt(0)" ::: "memory");
        __builtin_amdgcn_sched_barrier(0);
        __builtin_amdgcn_s_barrier();
        // A fragment from x-slab (swizzled chunks)
        f32x4 xa0 = *reinterpret_cast<const f32x4*>(&xslab[arow * 32 + (((2 * g) ^ (arow & 7)) * 4)]);
        f32x4 xa1 = *reinterpret_cast<const f32x4*>(&xslab[arow * 32 + (((2 * g + 1) ^ (arow & 7)) * 4)]);
        union { u16 u[8]; bf16x8 bv; } af;
#pragma unroll
        for (int t = 0; t < 4; ++t) { af.u[t] = f2bf(xa0[t]); af.u[4 + t] = f2bf(xa1[t]); }
        asm volatile("s_waitcnt lgkmcnt(0)" ::: "memory");
        __builtin_amdgcn_sched_barrier(0);
        __builtin_amdgcn_s_barrier();            // all waves consumed x-slab
        // issue next-step stages (x-slab now safe to overwrite; W into other buffer)
        int kn = (kk + 1 < 24) ? kk + 1 : 0;
        stageX(kn);
        stageW(buf ^ 1, kn);
        // compute on current W slab
#pragma unroll
        for (int y = 0; y < 3; ++y)
#pragma unroll
            for (int f = 0; f < 8; ++f) {
                int row = y * 128 + f * 16 + r;
                bf16x8 wf = ld8(&wslab[buf][row * 32 + ((g ^ (r & 3)) * 8)]);
                acc[y][f] = mfma16(af.bv, wf, acc[y][f]);
            }
        buf ^= 1;
    }
    asm volatile("s_waitcnt vmcnt(0)" ::: "memory");

    const float QSC = 0.1275174366f; // log2(e)/sqrt(128)
#pragma unroll
    for (int f = 0; f < 8; ++f)
#pragma unroll
        for (int i = 0; i < 4; ++i) {
            int mrow = m0 + wave * 16 + 4 * g + i;
            Qb[(size_t)mrow * D_OUT + f * 16 + r] = f2bf(acc[0][f][i] * QSC);
            Kb[(size_t)mrow * D_OUT + f * 16 + r] = f2bf(acc[1][f][i]);
            Vt[((size_t)((mrow >> 12) * D_OUT + f * 16 + r)) * S_LEN + (mrow & 4095)] = f2bf(acc[2][f][i]);
        }
}

// ---------------- Kernel 3: causal flash attention ----------------
// grid (64, 4), block 128 = 2 waves x 32 Q-rows (Q-tile 64). Shared KV stream:
// K dbuf LDS + V^T single-buf LDS via global_load_lds w/ pre-swizzled source,
// counted-vmcnt pipeline, raw s_barriers (no vmcnt(0) drain in loop).
__global__ __launch_bounds__(128) void attn_kernel(const u16* __restrict__ Qb, const u16* __restrict__ Kb,
                                                   const u16* __restrict__ Vt, float* __restrict__ out) {
    __shared__ __align__(16) u16 kbuf[2][64 * 128]; // [key][128d], 256B rows, chunk^=(row&7)
    __shared__ __align__(16) u16 vbuf[128 * 64];    // [d][64key], 128B rows, chunk^=(row&7)
    __shared__ __align__(16) u16 pbuf[2][32 * 72];  // per-wave P, padded stride 72

    const int wave = threadIdx.x >> 6, lane = threadIdx.x & 63;
    const int r = lane & 15, g = lane >> 4;
    const int b = blockIdx.y;
    const int tile = blockIdx.x;
    const int q0 = tile * 64;
    const int n = tile + 1;

    const u16* Kp = Kb + (size_t)b * S_LEN * D_OUT;
    const u16* Vp = Vt + (size_t)b * D_OUT * S_LEN;

    // Q fragments: wave rows q0+32*wave .. +32 (2 rowblocks of 16)
    bf16x8 qf[2][4];
#pragma unroll
    for (int rb = 0; rb < 2; ++rb)
#pragma unroll
        for (int kk = 0; kk < 4; ++kk)
            qf[rb][kk] = ld8(Qb + ((size_t)(b * S_LEN + q0 + wave * 32 + rb * 16 + r)) * D_OUT + kk * 32 + 8 * g);

    f32x4 o[2][8];
    float m_[2][4], l_[2][4];
#pragma unroll
    for (int rb = 0; rb < 2; ++rb) {
#pragma unroll
        for (int f = 0; f < 8; ++f) o[rb][f] = f32x4{0.f, 0.f, 0.f, 0.f};
#pragma unroll
        for (int i = 0; i < 4; ++i) { m_[rb][i] = -1e30f; l_[rb][i] = 0.f; }
    }

    const int ksub = lane >> 4, kch = lane & 15;
    const int vsub = lane >> 3, vch = lane & 7;

    auto stageK = [&](int bb, int k0) {
#pragma unroll
        for (int i = 0; i < 8; ++i) {
            int c = i * 2 + wave;                 // 0..15, 1KB chunks (4 key-rows)
            int row = c * 4 + ksub;
            const u16* src = Kp + (size_t)(k0 + row) * D_OUT + ((kch ^ (row & 7)) * 8);
            gload16(src, &kbuf[bb][c * 512]);
        }
    };
    auto stageV = [&](int k0) {
#pragma unroll
        for (int i = 0; i < 8; ++i) {
            int c = i * 2 + wave;                 // 0..15, 1KB chunks (8 d-rows)
            int row = c * 8 + vsub;
            const u16* src = Vp + (size_t)row * S_LEN + k0 + ((vch ^ (row & 7)) * 8);
            gload16(src, &vbuf[c * 512]);
        }
    };

    stageK(0, 0);
    int buf = 0;
    for (int j = 0; j < n; ++j) {
        const int k0 = j * 64;
        stageV(k0);
        stageK(buf ^ 1, (j + 1 < n) ? k0 + 64 : 0); // dummy on last iter keeps counts uniform
        asm volatile("s_waitcnt vmcnt(16)" ::: "memory"); // K(j) done; V(j)+K(j+1) in flight
        __builtin_amdgcn_sched_barrier(0);
        __builtin_amdgcn_s_barrier();

        // ---- S = Q K^T ----
        f32x4 s[2][4];
#pragma unroll
        for (int rb = 0; rb < 2; ++rb)
#pragma unroll
            for (int f = 0; f < 4; ++f) s[rb][f] = f32x4{0.f, 0.f, 0.f, 0.f};
#pragma unroll
        for (int kk = 0; kk < 4; ++kk)
#pragma unroll
            for (int f = 0; f < 4; ++f) {
                bf16x8 kf = ld8(&kbuf[buf][(f * 16 + r) * 128 + (((kk * 4 + g) ^ (r & 7)) * 8)]);
                s[0][f] = mfma16(qf[0][kk], kf, s[0][f]);
                s[1][f] = mfma16(qf[1][kk], kf, s[1][f]);
            }

        // ---- online softmax (log2 domain; scale folded into Q) ----
#pragma unroll
        for (int rb = 0; rb < 2; ++rb) {
            const int qrb = q0 + wave * 32 + rb * 16;
            if (k0 + 63 > qrb) {
#pragma unroll
                for (int f = 0; f < 4; ++f)
#pragma unroll
                    for (int i = 0; i < 4; ++i) {
                        int key = k0 + f * 16 + r;
                        int qrow = qrb + 4 * g + i;
                        if (key > qrow) s[rb][f][i] = -1e30f;
                    }
            }
            float pm[4], al[4], rs[4];
#pragma unroll
            for (int i = 0; i < 4; ++i) {
                pm[i] = fmaxf(fmaxf(s[rb][0][i], s[rb][1][i]), fmaxf(s[rb][2][i], s[rb][3][i]));
                pm[i] = red16_max(pm[i]);
                float mn = fmaxf(m_[rb][i], pm[i]);
                al[i] = exp2f(m_[rb][i] - mn);
                m_[rb][i] = mn;
                rs[i] = 0.f;
            }
#pragma unroll
            for (int f = 0; f < 4; ++f)
#pragma unroll
                for (int i = 0; i < 4; ++i) {
                    float p = exp2f(s[rb][f][i] - m_[rb][i]);
                    s[rb][f][i] = p;
                    rs[i] += p;
                }
#pragma unroll
            for (int i = 0; i < 4; ++i) {
                rs[i] = red16_sum(rs[i]);
                l_[rb][i] = l_[rb][i] * al[i] + rs[i];
            }
#pragma unroll
            for (int f = 0; f < 8; ++f)
#pragma unroll
                for (int i = 0; i < 4; ++i) o[rb][f][i] *= al[i];
            // P -> LDS (truncating bf16 convert)
#pragma unroll
            for (int f = 0; f < 4; ++f)
#pragma unroll
                for (int i = 0; i < 4; ++i)
                    pbuf[wave][(rb * 16 + 4 * g + i) * 72 + f * 16 + r] =
                        (u16)(__float_as_uint(s[rb][f][i]) >> 16);
        }
        asm volatile("s_waitcnt lgkmcnt(0)" ::: "memory");
        __builtin_amdgcn_sched_barrier(0);
        bf16x8 pa[2][2];
#pragma unroll
        for (int rb = 0; rb < 2; ++rb)
#pragma unroll
            for (int kk2 = 0; kk2 < 2; ++kk2)
                pa[rb][kk2] = ld8(&pbuf[wave][(rb * 16 + r) * 72 + kk2 * 32 + 8 * g]);

        asm volatile("s_waitcnt vmcnt(8)" ::: "memory"); // V(j) done; K(j+1) still in flight
        __builtin_amdgcn_sched_barrier(0);
        __builtin_amdgcn_s_barrier();

        // ---- O += P V ----
#pragma unroll
        for (int kk2 = 0; kk2 < 2; ++kk2)
#pragma unroll
            for (int f = 0; f < 8; ++f) {
                bf16x8 vf = ld8(&vbuf[(f * 16 + r) * 64 + (((kk2 * 4 + g) ^ (r & 7)) * 8)]);
                o[0][f] = mfma16(pa[0][kk2], vf, o[0][f]);
                o[1][f] = mfma16(pa[1][kk2], vf, o[1][f]);
            }
        __builtin_amdgcn_s_barrier(); // vbuf reads done before next iter's stageV
        buf ^= 1;
    }
    asm volatile("s_waitcnt vmcnt(0)" ::: "memory");

    // ---- epilogue: each wave owns its 32 rows ----
    float* op = out + ((size_t)(b * S_LEN + q0 + wave * 32)) * D_OUT;
#pragma unroll
    for (int rb = 0; rb < 2; ++rb)
#pragma unroll
        for (int i = 0; i < 4; ++i) {
            float inv = 1.0f / l_[rb][i];
#pragma unroll
            for (int f = 0; f < 8; ++f)
                op[(size_t)(rb * 16 + 4 * g + i) * D_OUT + f * 16 + r] = o[rb][f][i] * inv;
        }
}

extern "C" void kernel_launch(void* const* d_in, const int* in_sizes, int n_in,
                              void* d_out, int out_size, void* d_ws, size_t ws_size,
                              hipStream_t stream) {
    const float* x  = (const float*)d_in[0];
    const float* Wq = (const float*)d_in[1];
    const float* Wk = (const float*)d_in[2];
    const float* Wv = (const float*)d_in[3];
    float* out = (float*)d_out;

    // workspace layout (bf16 ushorts): Q | K | V^T | W^T  = ~12.6 MiB
    u16* Qb = (u16*)d_ws;
    u16* Kb = Qb + (size_t)M_TOTAL * D_OUT;
    u16* Vt = Kb + (size_t)M_TOTAL * D_OUT;
    u16* Wt = Vt + (size_t)M_TOTAL * D_OUT;

    wt_kernel<<<72, 256, 0, stream>>>(Wq, Wk, Wv, Wt);
    qkv_kernel<<<256, 256, 0, stream>>>(x, Wt, Qb, Kb, Vt);
    attn_kernel<<<dim3(S_LEN / 64, NB), 128, 0, stream>>>(Qb, Kb, Vt, out);
}

// Round 5
// 152.549 us; speedup vs baseline: 1.7932x; 1.5043x over previous
//
#include <hip/hip_runtime.h>
#include <stdint.h>

typedef unsigned short u16;
typedef __bf16 bf16;
typedef bf16 bf16x8 __attribute__((ext_vector_type(8)));
typedef float f32x4 __attribute__((ext_vector_type(4)));
typedef uint32_t u32x4 __attribute__((ext_vector_type(4)));

// ---- constants: B=4, S=4096, D_IN=768, D_OUT=128 ----
#define S_LEN 4096
#define D_IN 768
#define D_OUT 128
#define NB 4
#define M_TOTAL (NB * S_LEN) // 16384

static __device__ __forceinline__ u16 f2bf(float f) {
    union { float f; uint32_t u; } c; c.f = f;
    return (u16)((c.u + 0x7FFFu + ((c.u >> 16) & 1u)) >> 16);
}
static __device__ __forceinline__ float bf2f_lo(uint32_t w) { return __uint_as_float(w << 16); }
static __device__ __forceinline__ float bf2f_hi(uint32_t w) { return __uint_as_float(w & 0xFFFF0000u); }

static __device__ __forceinline__ bf16x8 ld8(const u16* p) {
    union { u32x4 v; bf16x8 b; } c;
    c.v = *reinterpret_cast<const u32x4*>(p);
    return c.b;
}

static __device__ __forceinline__ f32x4 mfma16(bf16x8 a, bf16x8 b, f32x4 c) {
    return __builtin_amdgcn_mfma_f32_16x16x32_bf16(a, b, c, 0, 0, 0);
}

// async global->LDS, 16B per lane; dest = uniform base + lane*16 (linear)
static __device__ __forceinline__ void gload16(const void* g, void* l) {
    __builtin_amdgcn_global_load_lds((const __attribute__((address_space(1))) uint32_t*)g,
                                     (__attribute__((address_space(3))) uint32_t*)l, 16, 0, 0);
}

// DPP-based 16-lane butterfly reduce (within each 16-lane row group).
template <int CTRL>
static __device__ __forceinline__ float dpp_f(float v) {
    return __int_as_float(__builtin_amdgcn_update_dpp(0, __float_as_int(v), CTRL, 0xF, 0xF, true));
}
static __device__ __forceinline__ float red16_max(float x) {
    x = fmaxf(x, dpp_f<0xB1>(x));
    x = fmaxf(x, dpp_f<0x4E>(x));
    x = fmaxf(x, dpp_f<0x141>(x));
    x = fmaxf(x, dpp_f<0x140>(x));
    return x;
}
static __device__ __forceinline__ float red16_sum(float x) {
    x += dpp_f<0xB1>(x);
    x += dpp_f<0x4E>(x);
    x += dpp_f<0x141>(x);
    x += dpp_f<0x140>(x);
    return x;
}

// ---------------- Kernel 1: W -> W^T bf16 via LDS transpose ----------------
__global__ __launch_bounds__(256) void wt_kernel(const float* __restrict__ Wq, const float* __restrict__ Wk,
                                                 const float* __restrict__ Wv, u16* __restrict__ Wt) {
    __shared__ u16 tl[128][40];
    const int w = blockIdx.x / 24;
    const int kc = (blockIdx.x % 24) * 32;
    const float* W = (w == 0) ? Wq : (w == 1) ? Wk : Wv;
#pragma unroll
    for (int p = 0; p < 4; ++p) {
        int kr = p * 8 + (threadIdx.x >> 5);
        int nc = (threadIdx.x & 31) * 4;
        float4 v = *reinterpret_cast<const float4*>(W + (size_t)(kc + kr) * D_OUT + nc);
        tl[nc + 0][kr] = f2bf(v.x); tl[nc + 1][kr] = f2bf(v.y);
        tl[nc + 2][kr] = f2bf(v.z); tl[nc + 3][kr] = f2bf(v.w);
    }
    __syncthreads();
    const int n = threadIdx.x >> 1, kh = (threadIdx.x & 1) * 16;
    u32x4* dst = reinterpret_cast<u32x4*>(Wt + (size_t)w * D_OUT * D_IN + (size_t)n * D_IN + kc + kh);
    const u32x4* src = reinterpret_cast<const u32x4*>(&tl[n][kh]);
    dst[0] = src[0];
    dst[1] = src[1];
}

// ---------------- Kernel 2: fused QKV projection ----------------
// grid 256, block 256 (4 waves x 16 rows). Counted-vmcnt double-buffered pipeline
// for BOTH W-slab and x-slab (no vmcnt(0) drain in loop). LDS exactly 64KB.
__global__ __launch_bounds__(256) void qkv_kernel(const float* __restrict__ x, const u16* __restrict__ Wt,
                                                  u16* __restrict__ Qb, u16* __restrict__ Kb,
                                                  u16* __restrict__ Vt) {
    __shared__ __align__(16) u16 wslab[2][384 * 32]; // [y*128+n][32k], 64B rows, slot^=(row&3)
    __shared__ __align__(16) float xslab[2][64 * 32]; // [row][32k] f32, 128B rows, slot^=(row&7)
    const int wave = threadIdx.x >> 6, lane = threadIdx.x & 63;
    const int r = lane & 15, g = lane >> 4;
    const int m0 = blockIdx.x * 64;

    f32x4 acc[3][8];
#pragma unroll
    for (int y = 0; y < 3; ++y)
#pragma unroll
        for (int f = 0; f < 8; ++f) acc[y][f] = f32x4{0.f, 0.f, 0.f, 0.f};

    auto stageW = [&](int bb, int kk) {
#pragma unroll
        for (int i = 0; i < 6; ++i) {
            int c = i * 4 + wave;                 // 0..23, 1KB chunks (16 rows)
            int row = c * 16 + (lane >> 2);
            const u16* src = Wt + (size_t)row * D_IN + kk * 32 + (((lane & 3) ^ (row & 3)) * 8);
            gload16(src, &wslab[bb][c * 512]);
        }
    };
    auto stageX = [&](int bb, int kk) {
#pragma unroll
        for (int i = 0; i < 2; ++i) {
            int c = i * 4 + wave;                 // 0..7, 1KB chunks (8 rows)
            int row = c * 8 + (lane >> 3);
            const float* src = x + (size_t)(m0 + row) * D_IN + kk * 32 + (((lane & 7) ^ (row & 7)) * 4);
            gload16(src, &xslab[bb][c * 256]);
        }
    };

    stageW(0, 0);
    stageX(0, 0);
    int buf = 0;
    const int arow = wave * 16 + r;
    for (int kk = 0; kk < 24; ++kk) {
        int kn = (kk + 1 < 24) ? kk + 1 : 0;     // dummy keeps vmcnt uniform
        stageX(buf ^ 1, kn);
        stageW(buf ^ 1, kn);
        asm volatile("s_waitcnt vmcnt(8)" ::: "memory"); // this wave's stage(buf,kk) done
        __builtin_amdgcn_sched_barrier(0);
        __builtin_amdgcn_s_barrier();            // -> everyone's stage(buf,kk) done
        f32x4 xa0 = *reinterpret_cast<const f32x4*>(&xslab[buf][arow * 32 + (((2 * g) ^ (arow & 7)) * 4)]);
        f32x4 xa1 = *reinterpret_cast<const f32x4*>(&xslab[buf][arow * 32 + (((2 * g + 1) ^ (arow & 7)) * 4)]);
        union { u16 u[8]; bf16x8 bv; } af;
#pragma unroll
        for (int t = 0; t < 4; ++t) { af.u[t] = f2bf(xa0[t]); af.u[4 + t] = f2bf(xa1[t]); }
#pragma unroll
        for (int y = 0; y < 3; ++y)
#pragma unroll
            for (int f = 0; f < 8; ++f) {
                int row = y * 128 + f * 16 + r;
                bf16x8 wf = ld8(&wslab[buf][row * 32 + ((g ^ (r & 3)) * 8)]);
                acc[y][f] = mfma16(af.bv, wf, acc[y][f]);
            }
        __builtin_amdgcn_s_barrier();            // all reads of buf done before next overwrite
        buf ^= 1;
    }

    const float QSC = 0.1275174366f; // log2(e)/sqrt(128) folded into Q
#pragma unroll
    for (int f = 0; f < 8; ++f)
#pragma unroll
        for (int i = 0; i < 4; ++i) {
            int mrow = m0 + wave * 16 + 4 * g + i;
            Qb[(size_t)mrow * D_OUT + f * 16 + r] = f2bf(acc[0][f][i] * QSC);
            Kb[(size_t)mrow * D_OUT + f * 16 + r] = f2bf(acc[1][f][i]);
            Vt[((size_t)((mrow >> 12) * D_OUT + f * 16 + r)) * S_LEN + (mrow & 4095)] = f2bf(acc[2][f][i]);
        }
}

// ---------------- Kernel 3: causal flash attention, global KV-split ----------------
// grid (32*nsplit, 4), block 256 = 4 waves x 32 rows (Q-tile 128). Split s takes KV
// tiles j == s (mod nsplit). K dbuf + V single-buf LDS via global_load_lds, counted
// vmcnt pipeline. Writes (m,l,O~) partials (or out directly when nsplit==1).
__global__ __launch_bounds__(256) void attn_kernel(const u16* __restrict__ Qb, const u16* __restrict__ Kb,
                                                   const u16* __restrict__ Vt, u16* __restrict__ Po,
                                                   float* __restrict__ Pml, float* __restrict__ out,
                                                   int nsplit) {
    __shared__ __align__(16) u16 kbuf[2][64 * 128]; // [key][128d], 256B rows, slot^=(row&7)
    __shared__ __align__(16) u16 vbuf[128 * 64];    // [d][64key], 128B rows, slot^=(row&7)
    __shared__ __align__(16) u16 pbuf[4][32 * 64];  // per-wave P, 128B rows, slot^=(row&7)

    const int wave = threadIdx.x >> 6, lane = threadIdx.x & 63;
    const int r = lane & 15, g = lane >> 4;
    const int b = blockIdx.y;
    const int t = 31 - (int)(blockIdx.x & 31);    // LPT: longest tiles first
    const int s = (int)blockIdx.x >> 5;
    const int nj = 2 * t + 2;                     // KV tiles for this Q-tile
    if (s >= nj) return;
    const int qw0 = t * 128 + wave * 32;

    const u16* Kp = Kb + (size_t)b * S_LEN * D_OUT;
    const u16* Vp = Vt + (size_t)b * D_OUT * S_LEN;

    bf16x8 qf[2][4];
#pragma unroll
    for (int rb = 0; rb < 2; ++rb)
#pragma unroll
        for (int kk = 0; kk < 4; ++kk)
            qf[rb][kk] = ld8(Qb + ((size_t)(b * S_LEN + qw0 + rb * 16 + r)) * D_OUT + kk * 32 + 8 * g);

    f32x4 o[2][8];
    float m_[2][4], l_[2][4];
#pragma unroll
    for (int rb = 0; rb < 2; ++rb) {
#pragma unroll
        for (int f = 0; f < 8; ++f) o[rb][f] = f32x4{0.f, 0.f, 0.f, 0.f};
#pragma unroll
        for (int i = 0; i < 4; ++i) { m_[rb][i] = -1e30f; l_[rb][i] = 0.f; }
    }

    auto stageK = [&](int bb, int k0) {
#pragma unroll
        for (int i = 0; i < 4; ++i) {
            int c = i * 4 + wave;                 // 0..15, 1KB chunks (4 key-rows)
            int row = c * 4 + (lane >> 4);
            const u16* src = Kp + (size_t)(k0 + row) * D_OUT + (((lane & 15) ^ (row & 7)) * 8);
            gload16(src, &kbuf[bb][c * 512]);
        }
    };
    auto stageV = [&](int k0) {
#pragma unroll
        for (int i = 0; i < 4; ++i) {
            int c = i * 4 + wave;                 // 0..15, 1KB chunks (8 d-rows)
            int row = c * 8 + (lane >> 3);
            const u16* src = Vp + (size_t)row * S_LEN + k0 + (((lane & 7) ^ (row & 7)) * 8);
            gload16(src, &vbuf[c * 512]);
        }
    };

    stageK(0, s * 64);
    int buf = 0;
    for (int j = s; j < nj; j += nsplit) {
        const int k0 = j * 64;
        stageV(k0);
        const int j2 = j + nsplit;
        stageK(buf ^ 1, (j2 < nj) ? j2 * 64 : 0); // dummy keeps counts uniform
        asm volatile("s_waitcnt vmcnt(8)" ::: "memory"); // K(j) done; V(j)+K(next) in flight
        __builtin_amdgcn_sched_barrier(0);
        __builtin_amdgcn_s_barrier();

        // ---- S = Q K^T ----
        f32x4 sc[2][4];
#pragma unroll
        for (int rb = 0; rb < 2; ++rb)
#pragma unroll
            for (int f = 0; f < 4; ++f) sc[rb][f] = f32x4{0.f, 0.f, 0.f, 0.f};
#pragma unroll
        for (int kk = 0; kk < 4; ++kk)
#pragma unroll
            for (int f = 0; f < 4; ++f) {
                bf16x8 kf = ld8(&kbuf[buf][(f * 16 + r) * 128 + (((kk * 4 + g) ^ (r & 7)) * 8)]);
                sc[0][f] = mfma16(qf[0][kk], kf, sc[0][f]);
                sc[1][f] = mfma16(qf[1][kk], kf, sc[1][f]);
            }

        // ---- online softmax (log2 domain; scale folded into Q) ----
#pragma unroll
        for (int rb = 0; rb < 2; ++rb) {
            const int qrb = qw0 + rb * 16;
            if (k0 + 63 > qrb) {
#pragma unroll
                for (int f = 0; f < 4; ++f)
#pragma unroll
                    for (int i = 0; i < 4; ++i) {
                        int key = k0 + f * 16 + r;
                        int qrow = qrb + 4 * g + i;
                        if (key > qrow) sc[rb][f][i] = -1e30f;
                    }
            }
            float pm[4], al[4], rs[4];
#pragma unroll
            for (int i = 0; i < 4; ++i) {
                pm[i] = fmaxf(fmaxf(sc[rb][0][i], sc[rb][1][i]), fmaxf(sc[rb][2][i], sc[rb][3][i]));
                pm[i] = red16_max(pm[i]);
                float mn = fmaxf(fmaxf(m_[rb][i], pm[i]), -60000.f); // floor: fully-masked tile -> p=0
                al[i] = exp2f(m_[rb][i] - mn);
                m_[rb][i] = mn;
                rs[i] = 0.f;
            }
#pragma unroll
            for (int f = 0; f < 4; ++f)
#pragma unroll
                for (int i = 0; i < 4; ++i) {
                    float p = exp2f(sc[rb][f][i] - m_[rb][i]);
                    sc[rb][f][i] = p;
                    rs[i] += p;
                }
#pragma unroll
            for (int i = 0; i < 4; ++i) {
                rs[i] = red16_sum(rs[i]);
                l_[rb][i] = l_[rb][i] * al[i] + rs[i];
            }
#pragma unroll
            for (int f = 0; f < 8; ++f)
#pragma unroll
                for (int i = 0; i < 4; ++i) o[rb][f][i] *= al[i];
            // P -> LDS (truncating convert), XOR-swizzled slots
#pragma unroll
            for (int f = 0; f < 4; ++f)
#pragma unroll
                for (int i = 0; i < 4; ++i) {
                    int rowl = rb * 16 + 4 * g + i;
                    int slot8 = (f * 2 + (r >> 3)) ^ (rowl & 7);
                    pbuf[wave][rowl * 64 + slot8 * 8 + (r & 7)] =
                        (u16)(__float_as_uint(sc[rb][f][i]) >> 16);
                }
        }
        asm volatile("s_waitcnt lgkmcnt(0)" ::: "memory");
        __builtin_amdgcn_sched_barrier(0);
        bf16x8 pa[2][2];
#pragma unroll
        for (int rb = 0; rb < 2; ++rb)
#pragma unroll
            for (int kk2 = 0; kk2 < 2; ++kk2) {
                int rowl = rb * 16 + r;
                pa[rb][kk2] = ld8(&pbuf[wave][rowl * 64 + (((kk2 * 4 + g) ^ (rowl & 7)) * 8)]);
            }

        asm volatile("s_waitcnt vmcnt(4)" ::: "memory"); // V(j) done; K(next) still in flight
        __builtin_amdgcn_sched_barrier(0);
        __builtin_amdgcn_s_barrier();

        // ---- O += P V ----
#pragma unroll
        for (int kk2 = 0; kk2 < 2; ++kk2)
#pragma unroll
            for (int f = 0; f < 8; ++f) {
                bf16x8 vf = ld8(&vbuf[(f * 16 + r) * 64 + (((kk2 * 4 + g) ^ (r & 7)) * 8)]);
                o[0][f] = mfma16(pa[0][kk2], vf, o[0][f]);
                o[1][f] = mfma16(pa[1][kk2], vf, o[1][f]);
            }
        __builtin_amdgcn_s_barrier(); // vbuf reads done before next stageV
        buf ^= 1;
    }

    if (nsplit == 1) {
        float* op = out + ((size_t)(b * S_LEN + qw0)) * D_OUT;
#pragma unroll
        for (int rb = 0; rb < 2; ++rb)
#pragma unroll
            for (int i = 0; i < 4; ++i) {
                float inv = 1.0f / l_[rb][i];
#pragma unroll
                for (int f = 0; f < 8; ++f)
                    op[(size_t)(rb * 16 + 4 * g + i) * D_OUT + f * 16 + r] = o[rb][f][i] * inv;
            }
    } else {
        const int pt = (b * 32 + t) * nsplit + s;
        u16* po = Po + (size_t)pt * (128 * 128);
        float* pml = Pml + (size_t)pt * 256;
#pragma unroll
        for (int rb = 0; rb < 2; ++rb)
#pragma unroll
            for (int f = 0; f < 8; ++f)
#pragma unroll
                for (int i = 0; i < 4; ++i)
                    po[(size_t)(wave * 32 + rb * 16 + 4 * g + i) * 128 + f * 16 + r] = f2bf(o[rb][f][i]);
        if (r == 0) {
#pragma unroll
            for (int rb = 0; rb < 2; ++rb)
#pragma unroll
                for (int i = 0; i < 4; ++i) {
                    int row = wave * 32 + rb * 16 + 4 * g + i;
                    pml[row * 2 + 0] = m_[rb][i];
                    pml[row * 2 + 1] = l_[rb][i];
                }
        }
    }
}

// ---------------- Kernel 4: split merge ----------------
// grid 1024, block 256: thread -> (row, 8 cols). out = sum(w_s*O~_s) / sum(w_s*l_s).
__global__ __launch_bounds__(256) void merge_kernel(const u16* __restrict__ Po, const float* __restrict__ Pml,
                                                    float* __restrict__ out, int nsplit) {
    const int gr = blockIdx.x * 16 + (threadIdx.x >> 4);
    const int c0 = (threadIdx.x & 15) * 8;
    const int b = gr >> 12, rr = gr & 4095;
    const int t = rr >> 7, row = rr & 127;
    const int ns = min(nsplit, 2 * t + 2);
    const size_t pbase = (size_t)(b * 32 + t) * nsplit;

    float m[4], l[4], w[4];
    float mstar = -1e30f;
#pragma unroll
    for (int s = 0; s < 4; ++s) {
        m[s] = -1e30f; l[s] = 0.f;
        if (s < ns) {
            const float* ml = Pml + (pbase + s) * 256 + row * 2;
            m[s] = ml[0]; l[s] = ml[1];
            mstar = fmaxf(mstar, m[s]);
        }
    }
    float L = 0.f;
#pragma unroll
    for (int s = 0; s < 4; ++s) {
        w[s] = (s < ns) ? exp2f(m[s] - mstar) : 0.f;
        L += w[s] * l[s];
    }
    const float inv = 1.0f / L;

    float acc[8];
#pragma unroll
    for (int k = 0; k < 8; ++k) acc[k] = 0.f;
#pragma unroll
    for (int s = 0; s < 4; ++s) {
        if (s < ns) {
            u32x4 pv = *reinterpret_cast<const u32x4*>(Po + (pbase + s) * (128 * 128) + (size_t)row * 128 + c0);
#pragma unroll
            for (int k = 0; k < 4; ++k) {
                acc[2 * k + 0] += w[s] * bf2f_lo(pv[k]);
                acc[2 * k + 1] += w[s] * bf2f_hi(pv[k]);
            }
        }
    }
    float* op = out + (size_t)gr * D_OUT + c0;
    float4 v0, v1;
    v0.x = acc[0] * inv; v0.y = acc[1] * inv; v0.z = acc[2] * inv; v0.w = acc[3] * inv;
    v1.x = acc[4] * inv; v1.y = acc[5] * inv; v1.z = acc[6] * inv; v1.w = acc[7] * inv;
    *reinterpret_cast<float4*>(op) = v0;
    *reinterpret_cast<float4*>(op + 4) = v1;
}

extern "C" void kernel_launch(void* const* d_in, const int* in_sizes, int n_in,
                              void* d_out, int out_size, void* d_ws, size_t ws_size,
                              hipStream_t stream) {
    const float* x  = (const float*)d_in[0];
    const float* Wq = (const float*)d_in[1];
    const float* Wk = (const float*)d_in[2];
    const float* Wv = (const float*)d_in[3];
    float* out = (float*)d_out;

    // ws layout (u16): Q | K | V^T | W^T | Po | Pml
    u16* Qb = (u16*)d_ws;
    u16* Kb = Qb + (size_t)M_TOTAL * D_OUT;       // 2,097,152 elems each
    u16* Vt = Kb + (size_t)M_TOTAL * D_OUT;
    u16* Wt = Vt + (size_t)M_TOTAL * D_OUT;

    // pick split factor by workspace size: base 13.17MB + nsplit*4.33MB
    const unsigned long long base = (3ULL * M_TOTAL * D_OUT + 3ULL * D_OUT * D_IN) * 2ULL;
    int nsplit = 4;
    if (ws_size < base + 4ULL * 4325376ULL) nsplit = 2;
    if (ws_size < base + 2ULL * 4325376ULL) nsplit = 1;

    u16* Po = Wt + (size_t)3 * D_OUT * D_IN;
    float* Pml = (float*)(Po + (size_t)nsplit * 128 * 128 * 128);

    wt_kernel<<<72, 256, 0, stream>>>(Wq, Wk, Wv, Wt);
    qkv_kernel<<<256, 256, 0, stream>>>(x, Wt, Qb, Kb, Vt);
    attn_kernel<<<dim3(32 * nsplit, NB), 256, 0, stream>>>(Qb, Kb, Vt, Po, Pml, out, nsplit);
    if (nsplit > 1)
        merge_kernel<<<M_TOTAL / 16, 256, 0, stream>>>(Po, Pml, out, nsplit);
}

// Round 6
// 140.456 us; speedup vs baseline: 1.9475x; 1.0861x over previous
//
#include <hip/hip_runtime.h>
#include <stdint.h>

typedef unsigned short u16;
typedef uint32_t u32;
typedef __bf16 bf16;
typedef bf16 bf16x8 __attribute__((ext_vector_type(8)));
typedef float f32x4 __attribute__((ext_vector_type(4)));
typedef uint32_t u32x4 __attribute__((ext_vector_type(4)));

// ---- constants: B=4, S=4096, D_IN=768, D_OUT=128 ----
#define S_LEN 4096
#define D_IN 768
#define D_OUT 128
#define NB 4
#define M_TOTAL (NB * S_LEN) // 16384

static __device__ __forceinline__ u16 f2bf(float f) {
    union { float f; uint32_t u; } c; c.f = f;
    return (u16)((c.u + 0x7FFFu + ((c.u >> 16) & 1u)) >> 16);
}
static __device__ __forceinline__ float bf2f_lo(uint32_t w) { return __uint_as_float(w << 16); }
static __device__ __forceinline__ float bf2f_hi(uint32_t w) { return __uint_as_float(w & 0xFFFF0000u); }

static __device__ __forceinline__ bf16x8 ld8(const u16* p) {
    union { u32x4 v; bf16x8 b; } c;
    c.v = *reinterpret_cast<const u32x4*>(p);
    return c.b;
}

static __device__ __forceinline__ f32x4 mfma16(bf16x8 a, bf16x8 b, f32x4 c) {
    return __builtin_amdgcn_mfma_f32_16x16x32_bf16(a, b, c, 0, 0, 0);
}

// async global->LDS, 16B per lane; dest = uniform base + lane*16 (linear)
static __device__ __forceinline__ void gload16(const void* g, void* l) {
    __builtin_amdgcn_global_load_lds((const __attribute__((address_space(1))) uint32_t*)g,
                                     (__attribute__((address_space(3))) uint32_t*)l, 16, 0, 0);
}

static __device__ __forceinline__ float bpermf(int addr, float v) {
    return __int_as_float(__builtin_amdgcn_ds_bpermute(addr, __float_as_int(v)));
}
static __device__ __forceinline__ u32 bpermu(int addr, u32 v) {
    return (u32)__builtin_amdgcn_ds_bpermute(addr, (int)v);
}
// truncating bf16 pack: low16 = bf16(a), high16 = bf16(b), one v_perm_b32
static __device__ __forceinline__ u32 pk2(float a, float b) {
    return __builtin_amdgcn_perm(__float_as_uint(b), __float_as_uint(a), 0x07060302u);
}

// ---------------- Kernel 1: W -> W^T bf16 via LDS transpose ----------------
__global__ __launch_bounds__(256) void wt_kernel(const float* __restrict__ Wq, const float* __restrict__ Wk,
                                                 const float* __restrict__ Wv, u16* __restrict__ Wt) {
    __shared__ u16 tl[128][40];
    const int w = blockIdx.x / 24;
    const int kc = (blockIdx.x % 24) * 32;
    const float* W = (w == 0) ? Wq : (w == 1) ? Wk : Wv;
#pragma unroll
    for (int p = 0; p < 4; ++p) {
        int kr = p * 8 + (threadIdx.x >> 5);
        int nc = (threadIdx.x & 31) * 4;
        float4 v = *reinterpret_cast<const float4*>(W + (size_t)(kc + kr) * D_OUT + nc);
        tl[nc + 0][kr] = f2bf(v.x); tl[nc + 1][kr] = f2bf(v.y);
        tl[nc + 2][kr] = f2bf(v.z); tl[nc + 3][kr] = f2bf(v.w);
    }
    __syncthreads();
    const int n = threadIdx.x >> 1, kh = (threadIdx.x & 1) * 16;
    u32x4* dst = reinterpret_cast<u32x4*>(Wt + (size_t)w * D_OUT * D_IN + (size_t)n * D_IN + kc + kh);
    const u32x4* src = reinterpret_cast<const u32x4*>(&tl[n][kh]);
    dst[0] = src[0];
    dst[1] = src[1];
}

// ---------------- Kernel 2: fused QKV projection ----------------
__global__ __launch_bounds__(256) void qkv_kernel(const float* __restrict__ x, const u16* __restrict__ Wt,
                                                  u16* __restrict__ Qb, u16* __restrict__ Kb,
                                                  u16* __restrict__ Vt) {
    __shared__ __align__(16) u16 wslab[2][384 * 32]; // [y*128+n][32k], 64B rows, slot^=(row&3)
    __shared__ __align__(16) float xslab[2][64 * 32]; // [row][32k] f32, 128B rows, slot^=(row&7)
    const int wave = threadIdx.x >> 6, lane = threadIdx.x & 63;
    const int r = lane & 15, g = lane >> 4;
    const int m0 = blockIdx.x * 64;

    f32x4 acc[3][8];
#pragma unroll
    for (int y = 0; y < 3; ++y)
#pragma unroll
        for (int f = 0; f < 8; ++f) acc[y][f] = f32x4{0.f, 0.f, 0.f, 0.f};

    auto stageW = [&](int bb, int kk) {
#pragma unroll
        for (int i = 0; i < 6; ++i) {
            int c = i * 4 + wave;                 // 0..23, 1KB chunks (16 rows)
            int row = c * 16 + (lane >> 2);
            const u16* src = Wt + (size_t)row * D_IN + kk * 32 + (((lane & 3) ^ (row & 3)) * 8);
            gload16(src, &wslab[bb][c * 512]);
        }
    };
    auto stageX = [&](int bb, int kk) {
#pragma unroll
        for (int i = 0; i < 2; ++i) {
            int c = i * 4 + wave;                 // 0..7, 1KB chunks (8 rows)
            int row = c * 8 + (lane >> 3);
            const float* src = x + (size_t)(m0 + row) * D_IN + kk * 32 + (((lane & 7) ^ (row & 7)) * 4);
            gload16(src, &xslab[bb][c * 256]);
        }
    };

    stageW(0, 0);
    stageX(0, 0);
    int buf = 0;
    const int arow = wave * 16 + r;
    for (int kk = 0; kk < 24; ++kk) {
        int kn = (kk + 1 < 24) ? kk + 1 : 0;     // dummy keeps vmcnt uniform
        stageX(buf ^ 1, kn);
        stageW(buf ^ 1, kn);
        asm volatile("s_waitcnt vmcnt(8)" ::: "memory");
        __builtin_amdgcn_sched_barrier(0);
        __builtin_amdgcn_s_barrier();
        f32x4 xa0 = *reinterpret_cast<const f32x4*>(&xslab[buf][arow * 32 + (((2 * g) ^ (arow & 7)) * 4)]);
        f32x4 xa1 = *reinterpret_cast<const f32x4*>(&xslab[buf][arow * 32 + (((2 * g + 1) ^ (arow & 7)) * 4)]);
        union { u16 u[8]; bf16x8 bv; } af;
#pragma unroll
        for (int t = 0; t < 4; ++t) { af.u[t] = f2bf(xa0[t]); af.u[4 + t] = f2bf(xa1[t]); }
#pragma unroll
        for (int y = 0; y < 3; ++y)
#pragma unroll
            for (int f = 0; f < 8; ++f) {
                int row = y * 128 + f * 16 + r;
                bf16x8 wf = ld8(&wslab[buf][row * 32 + ((g ^ (r & 3)) * 8)]);
                acc[y][f] = mfma16(af.bv, wf, acc[y][f]);
            }
        __builtin_amdgcn_s_barrier();
        buf ^= 1;
    }

    const float QSC = 0.1275174366f; // log2(e)/sqrt(128) folded into Q
#pragma unroll
    for (int f = 0; f < 8; ++f)
#pragma unroll
        for (int i = 0; i < 4; ++i) {
            int mrow = m0 + wave * 16 + 4 * g + i;
            Qb[(size_t)mrow * D_OUT + f * 16 + r] = f2bf(acc[0][f][i] * QSC);
            Kb[(size_t)mrow * D_OUT + f * 16 + r] = f2bf(acc[1][f][i]);
            Vt[((size_t)((mrow >> 12) * D_OUT + f * 16 + r)) * S_LEN + (mrow & 4095)] = f2bf(acc[2][f][i]);
        }
}

// ---------------- Kernel 3: causal flash attention (swapped-operand, KV-split) ----------------
// grid (32*nsplit, 4), block 256 = 4 waves x 32 queries (Q-tile 128).
// S^T = mfma(K,Q): lane holds one query's scores -> softmax is per-thread + 2 bpermute.
// P^T packed to bf16 in-register (v_perm) and redistributed via ds_bpermute to PV B-frags.
// O^T = mfma(V^T, P^T). LDS = K dbuf (32KB) + V (16KB) = 48KB -> 3 blocks/CU.
// t = (y&2) ? x : 31-x pairs heavy+light tiles on the same CU.
__global__ __launch_bounds__(256, 3) void attn_kernel(const u16* __restrict__ Qb, const u16* __restrict__ Kb,
                                                      const u16* __restrict__ Vt, u16* __restrict__ Po,
                                                      float* __restrict__ Pml, float* __restrict__ out,
                                                      int nsplit) {
    __shared__ __align__(16) u16 kbuf[2][64 * 128]; // [key][128d], 256B rows, slot^=(row&7)
    __shared__ __align__(16) u16 vbuf[128 * 64];    // [d][64key], 128B rows, slot^=(row&7)

    const int wave = threadIdx.x >> 6, lane = threadIdx.x & 63;
    const int r = lane & 15, g = lane >> 4;
    const int b = blockIdx.y;
    const int xh = (int)(blockIdx.x & 31);
    const int t = (blockIdx.y & 2) ? xh : 31 - xh; // complementary CU pairing
    const int s = (int)blockIdx.x >> 5;
    const int nj = 2 * t + 2;
    if (s >= nj) return;
    const int qw0 = t * 128 + wave * 32;

    const u16* Kp = Kb + (size_t)b * S_LEN * D_OUT;
    const u16* Vp = Vt + (size_t)b * D_OUT * S_LEN;

    // Q as B-fragments (col=query on lane&15, k=d) -- same register layout as A-frag load
    bf16x8 qf[2][4];
#pragma unroll
    for (int rb = 0; rb < 2; ++rb)
#pragma unroll
        for (int kk = 0; kk < 4; ++kk)
            qf[rb][kk] = ld8(Qb + ((size_t)(b * S_LEN + qw0 + rb * 16 + r)) * D_OUT + kk * 32 + 8 * g);

    f32x4 o[2][8]; // o[rb][f][i] = O^T[d=16f+4g+i][q=qw0+rb*16+r]
    float m_[2], l_[2];
#pragma unroll
    for (int rb = 0; rb < 2; ++rb) {
#pragma unroll
        for (int f = 0; f < 8; ++f) o[rb][f] = f32x4{0.f, 0.f, 0.f, 0.f};
        m_[rb] = -1e30f; l_[rb] = 0.f;
    }

    // bpermute byte-addresses
    const int la4 = (r + 32 * (g & 1)) * 4;  // a-src: g' = (2g)&3
    const int lb4 = la4 + 64;                // b-src: g' = (2g+1)&3
    const int lx16 = (lane ^ 16) * 4, lx32 = (lane ^ 32) * 4;
    const bool hi = (g >= 2);                // f-select: g>=2 uses f2

    auto stageK = [&](int bb, int k0) {
#pragma unroll
        for (int i = 0; i < 4; ++i) {
            int c = i * 4 + wave;                 // 0..15, 1KB chunks (4 key-rows)
            int row = c * 4 + (lane >> 4);
            const u16* src = Kp + (size_t)(k0 + row) * D_OUT + (((lane & 15) ^ (row & 7)) * 8);
            gload16(src, &kbuf[bb][c * 512]);
        }
    };
    auto stageV = [&](int k0) {
#pragma unroll
        for (int i = 0; i < 4; ++i) {
            int c = i * 4 + wave;                 // 0..15, 1KB chunks (8 d-rows)
            int row = c * 8 + (lane >> 3);
            const u16* src = Vp + (size_t)row * S_LEN + k0 + (((lane & 7) ^ (row & 7)) * 8);
            gload16(src, &vbuf[c * 512]);
        }
    };

    stageK(0, s * 64);
    int buf = 0;
    for (int j = s; j < nj; j += nsplit) {
        const int k0 = j * 64;
        stageV(k0);
        const int j2 = j + nsplit;
        stageK(buf ^ 1, (j2 < nj) ? j2 * 64 : 0); // dummy keeps counts uniform
        asm volatile("s_waitcnt vmcnt(8)" ::: "memory"); // K(j) done; V(j)+K(next) in flight
        __builtin_amdgcn_sched_barrier(0);
        __builtin_amdgcn_s_barrier();

        // ---- S^T = K Q : thread holds S^T[key=k0+16f+4g+i][q=qw0+rb*16+r] ----
        f32x4 sv[2][4];
#pragma unroll
        for (int rb = 0; rb < 2; ++rb)
#pragma unroll
            for (int f = 0; f < 4; ++f) sv[rb][f] = f32x4{0.f, 0.f, 0.f, 0.f};
#pragma unroll
        for (int kk = 0; kk < 4; ++kk)
#pragma unroll
            for (int f = 0; f < 4; ++f) {
                bf16x8 kf = ld8(&kbuf[buf][(f * 16 + r) * 128 + (((kk * 4 + g) ^ (r & 7)) * 8)]);
                sv[0][f] = mfma16(kf, qf[0][kk], sv[0][f]);
                sv[1][f] = mfma16(kf, qf[1][kk], sv[1][f]);
            }

        // ---- per-query softmax + pack + redistribute ----
        bf16x8 pb[2][2];
#pragma unroll
        for (int rb = 0; rb < 2; ++rb) {
            const int qrb = qw0 + rb * 16;
            const int q = qrb + r;
            if (k0 + 63 > qrb) {
#pragma unroll
                for (int f = 0; f < 4; ++f)
#pragma unroll
                    for (int i = 0; i < 4; ++i)
                        if (k0 + 16 * f + 4 * g + i > q) sv[rb][f][i] = -1e30f;
            }
            float pm = -1e30f;
#pragma unroll
            for (int f = 0; f < 4; ++f)
#pragma unroll
                for (int i = 0; i < 4; ++i) pm = fmaxf(pm, sv[rb][f][i]);
            pm = fmaxf(pm, bpermf(lx16, pm));
            pm = fmaxf(pm, bpermf(lx32, pm));
            float mn = fmaxf(fmaxf(m_[rb], pm), -60000.f);
            float al = __builtin_amdgcn_exp2f(m_[rb] - mn);
            m_[rb] = mn;
            float rs = 0.f;
#pragma unroll
            for (int f = 0; f < 4; ++f)
#pragma unroll
                for (int i = 0; i < 4; ++i) {
                    float p = __builtin_amdgcn_exp2f(sv[rb][f][i] - mn);
                    sv[rb][f][i] = p;
                    rs += p;
                }
            rs += bpermf(lx16, rs);
            rs += bpermf(lx32, rs);
            l_[rb] = l_[rb] * al + rs;
#pragma unroll
            for (int f = 0; f < 8; ++f) o[rb][f] *= al;

            // pack P^T rows to bf16: pkl[f] = keys (4g+0,4g+1) of block f, pkh = (4g+2,4g+3)
            u32 pkl[4], pkh[4];
#pragma unroll
            for (int f = 0; f < 4; ++f) {
                pkl[f] = pk2(sv[rb][f][0], sv[rb][f][1]);
                pkh[f] = pk2(sv[rb][f][2], sv[rb][f][3]);
            }
            // B-frag for PV: thread (r,g) needs keys kk2*32+8g+0..7 for query r
            // key kk2*32+8g+j -> f = 2kk2+(g>>1), src lane a (j<4) / b (j>=4)
#pragma unroll
            for (int kk2 = 0; kk2 < 2; ++kk2) {
                const int f1 = 2 * kk2, f2 = 2 * kk2 + 1;
                u32 a1 = bpermu(la4, pkl[f1]), a2 = bpermu(la4, pkl[f2]);
                u32 b1 = bpermu(la4, pkh[f1]), b2 = bpermu(la4, pkh[f2]);
                u32 c1 = bpermu(lb4, pkl[f1]), c2 = bpermu(lb4, pkl[f2]);
                u32 d1 = bpermu(lb4, pkh[f1]), d2 = bpermu(lb4, pkh[f2]);
                union { u32x4 u; bf16x8 bv; } cc;
                cc.u = u32x4{hi ? a2 : a1, hi ? b2 : b1, hi ? c2 : c1, hi ? d2 : d1};
                pb[rb][kk2] = cc.bv;
            }
        }

        asm volatile("s_waitcnt vmcnt(4)" ::: "memory"); // V(j) done; K(next) still in flight
        __builtin_amdgcn_sched_barrier(0);
        __builtin_amdgcn_s_barrier();

        // ---- O^T += V^T P^T ----
#pragma unroll
        for (int kk2 = 0; kk2 < 2; ++kk2)
#pragma unroll
            for (int f = 0; f < 8; ++f) {
                bf16x8 vf = ld8(&vbuf[(f * 16 + r) * 64 + (((kk2 * 4 + g) ^ (r & 7)) * 8)]);
                o[0][f] = mfma16(vf, pb[0][kk2], o[0][f]);
                o[1][f] = mfma16(vf, pb[1][kk2], o[1][f]);
            }
        __builtin_amdgcn_s_barrier(); // vbuf reads done before next stageV
        buf ^= 1;
    }
    asm volatile("s_waitcnt vmcnt(0)" ::: "memory"); // drain dummy stages before LDS freed

    if (nsplit == 1) {
#pragma unroll
        for (int rb = 0; rb < 2; ++rb) {
            float inv = 1.0f / l_[rb];
            float* orow = out + ((size_t)(b * S_LEN + qw0 + rb * 16 + r)) * D_OUT;
#pragma unroll
            for (int f = 0; f < 8; ++f) {
                float4 v;
                v.x = o[rb][f][0] * inv; v.y = o[rb][f][1] * inv;
                v.z = o[rb][f][2] * inv; v.w = o[rb][f][3] * inv;
                *reinterpret_cast<float4*>(orow + 16 * f + 4 * g) = v;
            }
        }
    } else {
        const int pt = (b * 32 + t) * nsplit + s;
        u16* po = Po + (size_t)pt * (128 * 128);
        float* pml = Pml + (size_t)pt * 256;
#pragma unroll
        for (int rb = 0; rb < 2; ++rb) {
            const int row = wave * 32 + rb * 16 + r;
#pragma unroll
            for (int f = 0; f < 8; ++f) {
                u32 w0 = (u32)f2bf(o[rb][f][0]) | ((u32)f2bf(o[rb][f][1]) << 16);
                u32 w1 = (u32)f2bf(o[rb][f][2]) | ((u32)f2bf(o[rb][f][3]) << 16);
                uint2 ww; ww.x = w0; ww.y = w1;
                *reinterpret_cast<uint2*>(po + (size_t)row * 128 + 16 * f + 4 * g) = ww;
            }
            if (g == 0) {
                pml[row * 2 + 0] = m_[rb];
                pml[row * 2 + 1] = l_[rb];
            }
        }
    }
}

// ---------------- Kernel 4: split merge ----------------
__global__ __launch_bounds__(256) void merge_kernel(const u16* __restrict__ Po, const float* __restrict__ Pml,
                                                    float* __restrict__ out, int nsplit) {
    const int gr = blockIdx.x * 16 + (threadIdx.x >> 4);
    const int c0 = (threadIdx.x & 15) * 8;
    const int b = gr >> 12, rr = gr & 4095;
    const int t = rr >> 7, row = rr & 127;
    const int ns = min(nsplit, 2 * t + 2);
    const size_t pbase = (size_t)(b * 32 + t) * nsplit;

    float m[4], l[4], w[4];
    float mstar = -1e30f;
#pragma unroll
    for (int s = 0; s < 4; ++s) {
        m[s] = -1e30f; l[s] = 0.f;
        if (s < ns) {
            const float* ml = Pml + (pbase + s) * 256 + row * 2;
            m[s] = ml[0]; l[s] = ml[1];
            mstar = fmaxf(mstar, m[s]);
        }
    }
    float L = 0.f;
#pragma unroll
    for (int s = 0; s < 4; ++s) {
        w[s] = (s < ns) ? __builtin_amdgcn_exp2f(m[s] - mstar) : 0.f;
        L += w[s] * l[s];
    }
    const float inv = 1.0f / L;

    float acc[8];
#pragma unroll
    for (int k = 0; k < 8; ++k) acc[k] = 0.f;
#pragma unroll
    for (int s = 0; s < 4; ++s) {
        if (s < ns) {
            u32x4 pv = *reinterpret_cast<const u32x4*>(Po + (pbase + s) * (128 * 128) + (size_t)row * 128 + c0);
#pragma unroll
            for (int k = 0; k < 4; ++k) {
                acc[2 * k + 0] += w[s] * bf2f_lo(pv[k]);
                acc[2 * k + 1] += w[s] * bf2f_hi(pv[k]);
            }
        }
    }
    float* op = out + (size_t)gr * D_OUT + c0;
    float4 v0, v1;
    v0.x = acc[0] * inv; v0.y = acc[1] * inv; v0.z = acc[2] * inv; v0.w = acc[3] * inv;
    v1.x = acc[4] * inv; v1.y = acc[5] * inv; v1.z = acc[6] * inv; v1.w = acc[7] * inv;
    *reinterpret_cast<float4*>(op) = v0;
    *reinterpret_cast<float4*>(op + 4) = v1;
}

extern "C" void kernel_launch(void* const* d_in, const int* in_sizes, int n_in,
                              void* d_out, int out_size, void* d_ws, size_t ws_size,
                              hipStream_t stream) {
    const float* x  = (const float*)d_in[0];
    const float* Wq = (const float*)d_in[1];
    const float* Wk = (const float*)d_in[2];
    const float* Wv = (const float*)d_in[3];
    float* out = (float*)d_out;

    // ws layout (u16): Q | K | V^T | W^T | Po | Pml
    u16* Qb = (u16*)d_ws;
    u16* Kb = Qb + (size_t)M_TOTAL * D_OUT;
    u16* Vt = Kb + (size_t)M_TOTAL * D_OUT;
    u16* Wt = Vt + (size_t)M_TOTAL * D_OUT;

    const unsigned long long base = (3ULL * M_TOTAL * D_OUT + 3ULL * D_OUT * D_IN) * 2ULL;
    int nsplit = 4;
    if (ws_size < base + 4ULL * 4325376ULL) nsplit = 2;
    if (ws_size < base + 2ULL * 4325376ULL) nsplit = 1;

    u16* Po = Wt + (size_t)3 * D_OUT * D_IN;
    float* Pml = (float*)(Po + (size_t)nsplit * 128 * 128 * 128);

    wt_kernel<<<72, 256, 0, stream>>>(Wq, Wk, Wv, Wt);
    qkv_kernel<<<256, 256, 0, stream>>>(x, Wt, Qb, Kb, Vt);
    attn_kernel<<<dim3(32 * nsplit, NB), 256, 0, stream>>>(Qb, Kb, Vt, Po, Pml, out, nsplit);
    if (nsplit > 1)
        merge_kernel<<<M_TOTAL / 16, 256, 0, stream>>>(Po, Pml, out, nsplit);
}

// Round 9
// 127.117 us; speedup vs baseline: 2.1519x; 1.1049x over previous
//
#include <hip/hip_runtime.h>
#include <stdint.h>

typedef unsigned short u16;
typedef uint32_t u32;
typedef __bf16 bf16;
typedef bf16 bf16x8 __attribute__((ext_vector_type(8)));
typedef float f32x4 __attribute__((ext_vector_type(4)));
typedef uint32_t u32x4 __attribute__((ext_vector_type(4)));

// ---- constants: B=4, S=4096, D_IN=768, D_OUT=128 ----
#define S_LEN 4096
#define D_IN 768
#define D_OUT 128
#define NB 4
#define M_TOTAL (NB * S_LEN) // 16384

static __device__ __forceinline__ u16 f2bf(float f) {
    union { float f; uint32_t u; } c; c.f = f;
    return (u16)((c.u + 0x7FFFu + ((c.u >> 16) & 1u)) >> 16);
}
static __device__ __forceinline__ float bf2f_lo(uint32_t w) { return __uint_as_float(w << 16); }
static __device__ __forceinline__ float bf2f_hi(uint32_t w) { return __uint_as_float(w & 0xFFFF0000u); }

static __device__ __forceinline__ bf16x8 ld8(const u16* p) {
    union { u32x4 v; bf16x8 b; } c;
    c.v = *reinterpret_cast<const u32x4*>(p);
    return c.b;
}

static __device__ __forceinline__ f32x4 mfma16(bf16x8 a, bf16x8 b, f32x4 c) {
    return __builtin_amdgcn_mfma_f32_16x16x32_bf16(a, b, c, 0, 0, 0);
}

// async global->LDS, 16B per lane; dest = uniform base + lane*16 (linear)
static __device__ __forceinline__ void gload16(const void* g, void* l) {
    __builtin_amdgcn_global_load_lds((const __attribute__((address_space(1))) uint32_t*)g,
                                     (__attribute__((address_space(3))) uint32_t*)l, 16, 0, 0);
}

static __device__ __forceinline__ float bpermf(int addr, float v) {
    return __int_as_float(__builtin_amdgcn_ds_bpermute(addr, __float_as_int(v)));
}
static __device__ __forceinline__ u32 bpermu(int addr, u32 v) {
    return (u32)__builtin_amdgcn_ds_bpermute(addr, (int)v);
}
// truncating bf16 pack: low16 = bf16(a), high16 = bf16(b), one v_perm_b32
static __device__ __forceinline__ u32 pk2(float a, float b) {
    return __builtin_amdgcn_perm(__float_as_uint(b), __float_as_uint(a), 0x07060302u);
}

// ---------------- Kernel 1: W -> W^T bf16 via LDS transpose ----------------
__global__ __launch_bounds__(256) void wt_kernel(const float* __restrict__ Wq, const float* __restrict__ Wk,
                                                 const float* __restrict__ Wv, u16* __restrict__ Wt) {
    __shared__ u16 tl[128][40];
    const int w = blockIdx.x / 24;
    const int kc = (blockIdx.x % 24) * 32;
    const float* W = (w == 0) ? Wq : (w == 1) ? Wk : Wv;
#pragma unroll
    for (int p = 0; p < 4; ++p) {
        int kr = p * 8 + (threadIdx.x >> 5);
        int nc = (threadIdx.x & 31) * 4;
        float4 v = *reinterpret_cast<const float4*>(W + (size_t)(kc + kr) * D_OUT + nc);
        tl[nc + 0][kr] = f2bf(v.x); tl[nc + 1][kr] = f2bf(v.y);
        tl[nc + 2][kr] = f2bf(v.z); tl[nc + 3][kr] = f2bf(v.w);
    }
    __syncthreads();
    const int n = threadIdx.x >> 1, kh = (threadIdx.x & 1) * 16;
    u32x4* dst = reinterpret_cast<u32x4*>(Wt + (size_t)w * D_OUT * D_IN + (size_t)n * D_IN + kc + kh);
    const u32x4* src = reinterpret_cast<const u32x4*>(&tl[n][kh]);
    dst[0] = src[0];
    dst[1] = src[1];
}

// ---------------- Kernel 2: fused QKV projection, N-split ----------------
// grid (256,2), block 256 (4 waves x 16 rows). Each block computes 64 output cols
// (h*64..) of each of Q,K,V. LDS 40KB -> 4 blocks/CU.
__global__ __launch_bounds__(256) void qkv_kernel(const float* __restrict__ x, const u16* __restrict__ Wt,
                                                  u16* __restrict__ Qb, u16* __restrict__ Kb,
                                                  u16* __restrict__ Vt) {
    __shared__ __align__(16) u16 wslab[2][192 * 32];  // [y*64 + n'][32k], 64B rows, slot^=(row&3)
    __shared__ __align__(16) float xslab[2][64 * 32]; // [row][32k] f32, 128B rows, slot^=(row&7)
    const int wave = threadIdx.x >> 6, lane = threadIdx.x & 63;
    const int r = lane & 15, g = lane >> 4;
    const int m0 = blockIdx.x * 64;
    const int h = blockIdx.y;           // n-half

    f32x4 acc[3][4];
#pragma unroll
    for (int y = 0; y < 3; ++y)
#pragma unroll
        for (int f = 0; f < 4; ++f) acc[y][f] = f32x4{0.f, 0.f, 0.f, 0.f};

    auto stageW = [&](int bb, int kk) {
#pragma unroll
        for (int i = 0; i < 3; ++i) {
            int c = i * 4 + wave;                 // 0..11, 1KB chunks (16 rows)
            int rr = c * 16 + (lane >> 2);
            int gr = (rr >> 6) * 128 + h * 64 + (rr & 63);
            const u16* src = Wt + (size_t)gr * D_IN + kk * 32 + (((lane & 3) ^ (rr & 3)) * 8);
            gload16(src, &wslab[bb][c * 512]);
        }
    };
    auto stageX = [&](int bb, int kk) {
#pragma unroll
        for (int i = 0; i < 2; ++i) {
            int c = i * 4 + wave;                 // 0..7, 1KB chunks (8 rows)
            int row = c * 8 + (lane >> 3);
            const float* src = x + (size_t)(m0 + row) * D_IN + kk * 32 + (((lane & 7) ^ (row & 7)) * 4);
            gload16(src, &xslab[bb][c * 256]);
        }
    };

    stageW(0, 0);
    stageX(0, 0);
    int buf = 0;
    const int arow = wave * 16 + r;
    for (int kk = 0; kk < 24; ++kk) {
        int kn = (kk + 1 < 24) ? kk + 1 : 0;     // dummy keeps vmcnt uniform
        stageX(buf ^ 1, kn);
        stageW(buf ^ 1, kn);
        asm volatile("s_waitcnt vmcnt(5)" ::: "memory"); // this wave's stage(buf) done
        __builtin_amdgcn_sched_barrier(0);
        __builtin_amdgcn_s_barrier();
        f32x4 xa0 = *reinterpret_cast<const f32x4*>(&xslab[buf][arow * 32 + (((2 * g) ^ (arow & 7)) * 4)]);
        f32x4 xa1 = *reinterpret_cast<const f32x4*>(&xslab[buf][arow * 32 + (((2 * g + 1) ^ (arow & 7)) * 4)]);
        union { u16 u[8]; bf16x8 bv; } af;
#pragma unroll
        for (int t = 0; t < 4; ++t) { af.u[t] = f2bf(xa0[t]); af.u[4 + t] = f2bf(xa1[t]); }
#pragma unroll
        for (int y = 0; y < 3; ++y)
#pragma unroll
            for (int f = 0; f < 4; ++f) {
                int rr = y * 64 + f * 16 + r;
                bf16x8 wf = ld8(&wslab[buf][rr * 32 + ((g ^ (r & 3)) * 8)]);
                acc[y][f] = mfma16(af.bv, wf, acc[y][f]);
            }
        __builtin_amdgcn_s_barrier();
        buf ^= 1;
    }
    // Drain in-flight dummy global_load_lds before this workgroup retires (R7 lesson).
    asm volatile("s_waitcnt vmcnt(0)" ::: "memory");

    const float QSC = 0.1275174366f; // log2(e)/sqrt(128) folded into Q
#pragma unroll
    for (int f = 0; f < 4; ++f)
#pragma unroll
        for (int i = 0; i < 4; ++i) {
            int mrow = m0 + wave * 16 + 4 * g + i;
            int col = h * 64 + f * 16 + r;
            Qb[(size_t)mrow * D_OUT + col] = f2bf(acc[0][f][i] * QSC);
            Kb[(size_t)mrow * D_OUT + col] = f2bf(acc[1][f][i]);
            Vt[((size_t)((mrow >> 12) * D_OUT + col)) * S_LEN + (mrow & 4095)] = f2bf(acc[2][f][i]);
        }
}

// ---------------- Kernel 3: causal flash attention (swapped-operand, KV-split) ----------------
// grid (32*nsplit, 4), block 256 = 4 waves x 32 queries (Q-tile 128).
// S^T = mfma(K,Q); per-query softmax with R6-proven ds_bpermute ^16/^32 reduce;
// P^T packed (v_perm) + redistributed via ds_bpermute; O^T = mfma(V^T, P^T).
// nsplit=8 -> every block <= 8 KV iterations.
__global__ __launch_bounds__(256, 3) void attn_kernel(const u16* __restrict__ Qb, const u16* __restrict__ Kb,
                                                      const u16* __restrict__ Vt, u16* __restrict__ Po,
                                                      float* __restrict__ Pml, float* __restrict__ out,
                                                      int nsplit) {
    __shared__ __align__(16) u16 kbuf[2][64 * 128]; // [key][128d], 256B rows, slot^=(row&7)
    __shared__ __align__(16) u16 vbuf[128 * 64];    // [d][64key], 128B rows, slot^=(row&7)

    const int wave = threadIdx.x >> 6, lane = threadIdx.x & 63;
    const int r = lane & 15, g = lane >> 4;
    const int b = blockIdx.y;
    const int xh = (int)(blockIdx.x & 31);
    const int t = (blockIdx.y & 2) ? xh : 31 - xh; // complementary CU pairing
    const int s = (int)blockIdx.x >> 5;
    const int nj = 2 * t + 2;
    if (s >= nj) return;
    const int qw0 = t * 128 + wave * 32;

    const u16* Kp = Kb + (size_t)b * S_LEN * D_OUT;
    const u16* Vp = Vt + (size_t)b * D_OUT * S_LEN;

    // Q as B-fragments (col=query on lane&15, k=d)
    bf16x8 qf[2][4];
#pragma unroll
    for (int rb = 0; rb < 2; ++rb)
#pragma unroll
        for (int kk = 0; kk < 4; ++kk)
            qf[rb][kk] = ld8(Qb + ((size_t)(b * S_LEN + qw0 + rb * 16 + r)) * D_OUT + kk * 32 + 8 * g);

    f32x4 o[2][8]; // o[rb][f][i] = O^T[d=16f+4g+i][q=qw0+rb*16+r]
    float m_[2], l_[2];
#pragma unroll
    for (int rb = 0; rb < 2; ++rb) {
#pragma unroll
        for (int f = 0; f < 8; ++f) o[rb][f] = f32x4{0.f, 0.f, 0.f, 0.f};
        m_[rb] = -1e30f; l_[rb] = 0.f;
    }

    // bpermute byte-addresses
    const int la4 = (r + 32 * (g & 1)) * 4;  // a-src: g' in {0,2}
    const int lb4 = la4 + 64;                // b-src: g' in {1,3}
    const int lx16 = (lane ^ 16) * 4, lx32 = (lane ^ 32) * 4;
    const bool hi = (g >= 2);

    auto stageK = [&](int bb, int k0) {
#pragma unroll
        for (int i = 0; i < 4; ++i) {
            int c = i * 4 + wave;                 // 0..15, 1KB chunks (4 key-rows)
            int row = c * 4 + (lane >> 4);
            const u16* src = Kp + (size_t)(k0 + row) * D_OUT + (((lane & 15) ^ (row & 7)) * 8);
            gload16(src, &kbuf[bb][c * 512]);
        }
    };
    auto stageV = [&](int k0) {
#pragma unroll
        for (int i = 0; i < 4; ++i) {
            int c = i * 4 + wave;                 // 0..15, 1KB chunks (8 d-rows)
            int row = c * 8 + (lane >> 3);
            const u16* src = Vp + (size_t)row * S_LEN + k0 + (((lane & 7) ^ (row & 7)) * 8);
            gload16(src, &vbuf[c * 512]);
        }
    };

    stageK(0, s * 64);
    int buf = 0;
    for (int j = s; j < nj; j += nsplit) {
        const int k0 = j * 64;
        stageV(k0);
        const int j2 = j + nsplit;
        stageK(buf ^ 1, (j2 < nj) ? j2 * 64 : 0); // dummy keeps counts uniform
        asm volatile("s_waitcnt vmcnt(8)" ::: "memory"); // K(j) done; V(j)+K(next) in flight
        __builtin_amdgcn_sched_barrier(0);
        __builtin_amdgcn_s_barrier();

        // ---- S^T = K Q : thread holds S^T[key=k0+16f+4g+i][q=qw0+rb*16+r] ----
        f32x4 sv[2][4];
#pragma unroll
        for (int rb = 0; rb < 2; ++rb)
#pragma unroll
            for (int f = 0; f < 4; ++f) sv[rb][f] = f32x4{0.f, 0.f, 0.f, 0.f};
        __builtin_amdgcn_s_setprio(1);
#pragma unroll
        for (int kk = 0; kk < 4; ++kk)
#pragma unroll
            for (int f = 0; f < 4; ++f) {
                bf16x8 kf = ld8(&kbuf[buf][(f * 16 + r) * 128 + (((kk * 4 + g) ^ (r & 7)) * 8)]);
                sv[0][f] = mfma16(kf, qf[0][kk], sv[0][f]);
                sv[1][f] = mfma16(kf, qf[1][kk], sv[1][f]);
            }
        __builtin_amdgcn_s_setprio(0);

        // ---- per-query softmax (R6-proven bpermute reduce) + pack + redistribute ----
        bf16x8 pb[2][2];
#pragma unroll
        for (int rb = 0; rb < 2; ++rb) {
            const int qrb = qw0 + rb * 16;
            const int q = qrb + r;
            if (k0 + 63 > qrb) {
#pragma unroll
                for (int f = 0; f < 4; ++f)
#pragma unroll
                    for (int i = 0; i < 4; ++i)
                        if (k0 + 16 * f + 4 * g + i > q) sv[rb][f][i] = -1e30f;
            }
            float pm = -1e30f;
#pragma unroll
            for (int f = 0; f < 4; ++f)
#pragma unroll
                for (int i = 0; i < 4; ++i) pm = fmaxf(pm, sv[rb][f][i]);
            pm = fmaxf(pm, bpermf(lx16, pm));
            pm = fmaxf(pm, bpermf(lx32, pm));
            float mn = fmaxf(fmaxf(m_[rb], pm), -60000.f); // floor: fully-masked tile -> p=0
            float al = __builtin_amdgcn_exp2f(m_[rb] - mn);
            m_[rb] = mn;
            float rs = 0.f;
#pragma unroll
            for (int f = 0; f < 4; ++f)
#pragma unroll
                for (int i = 0; i < 4; ++i) {
                    float p = __builtin_amdgcn_exp2f(sv[rb][f][i] - mn);
                    sv[rb][f][i] = p;
                    rs += p;
                }
            rs += bpermf(lx16, rs);
            rs += bpermf(lx32, rs);
            l_[rb] = l_[rb] * al + rs;
#pragma unroll
            for (int f = 0; f < 8; ++f) o[rb][f] *= al;

            // pack P^T to bf16 pairs and redistribute to PV B-frags
            u32 pkl[4], pkh[4];
#pragma unroll
            for (int f = 0; f < 4; ++f) {
                pkl[f] = pk2(sv[rb][f][0], sv[rb][f][1]);
                pkh[f] = pk2(sv[rb][f][2], sv[rb][f][3]);
            }
#pragma unroll
            for (int kk2 = 0; kk2 < 2; ++kk2) {
                const int f1 = 2 * kk2, f2 = 2 * kk2 + 1;
                u32 a1 = bpermu(la4, pkl[f1]), a2 = bpermu(la4, pkl[f2]);
                u32 b1 = bpermu(la4, pkh[f1]), b2 = bpermu(la4, pkh[f2]);
                u32 c1 = bpermu(lb4, pkl[f1]), c2 = bpermu(lb4, pkl[f2]);
                u32 d1 = bpermu(lb4, pkh[f1]), d2 = bpermu(lb4, pkh[f2]);
                union { u32x4 u; bf16x8 bv; } cc;
                cc.u = u32x4{hi ? a2 : a1, hi ? b2 : b1, hi ? c2 : c1, hi ? d2 : d1};
                pb[rb][kk2] = cc.bv;
            }
        }

        asm volatile("s_waitcnt vmcnt(4)" ::: "memory"); // V(j) done; K(next) still in flight
        __builtin_amdgcn_sched_barrier(0);
        __builtin_amdgcn_s_barrier();

        // ---- O^T += V^T P^T ----
        __builtin_amdgcn_s_setprio(1);
#pragma unroll
        for (int kk2 = 0; kk2 < 2; ++kk2)
#pragma unroll
            for (int f = 0; f < 8; ++f) {
                bf16x8 vf = ld8(&vbuf[(f * 16 + r) * 64 + (((kk2 * 4 + g) ^ (r & 7)) * 8)]);
                o[0][f] = mfma16(vf, pb[0][kk2], o[0][f]);
                o[1][f] = mfma16(vf, pb[1][kk2], o[1][f]);
            }
        __builtin_amdgcn_s_setprio(0);
        __builtin_amdgcn_s_barrier(); // vbuf reads done before next stageV
        buf ^= 1;
    }
    asm volatile("s_waitcnt vmcnt(0)" ::: "memory"); // drain dummy stages before LDS freed

    if (nsplit == 1) {
#pragma unroll
        for (int rb = 0; rb < 2; ++rb) {
            float inv = 1.0f / l_[rb];
            float* orow = out + ((size_t)(b * S_LEN + qw0 + rb * 16 + r)) * D_OUT;
#pragma unroll
            for (int f = 0; f < 8; ++f) {
                float4 v;
                v.x = o[rb][f][0] * inv; v.y = o[rb][f][1] * inv;
                v.z = o[rb][f][2] * inv; v.w = o[rb][f][3] * inv;
                *reinterpret_cast<float4*>(orow + 16 * f + 4 * g) = v;
            }
        }
    } else {
        const int pt = (b * 32 + t) * nsplit + s;
        u16* po = Po + (size_t)pt * (128 * 128);
        float* pml = Pml + (size_t)pt * 256;
#pragma unroll
        for (int rb = 0; rb < 2; ++rb) {
            const int row = wave * 32 + rb * 16 + r;
#pragma unroll
            for (int f = 0; f < 8; ++f) {
                u32 w0 = (u32)f2bf(o[rb][f][0]) | ((u32)f2bf(o[rb][f][1]) << 16);
                u32 w1 = (u32)f2bf(o[rb][f][2]) | ((u32)f2bf(o[rb][f][3]) << 16);
                uint2 ww; ww.x = w0; ww.y = w1;
                *reinterpret_cast<uint2*>(po + (size_t)row * 128 + 16 * f + 4 * g) = ww;
            }
            if (g == 0) {
                pml[row * 2 + 0] = m_[rb];
                pml[row * 2 + 1] = l_[rb];
            }
        }
    }
}

// ---------------- Kernel 4: split merge (up to 8 splits) ----------------
__global__ __launch_bounds__(256) void merge_kernel(const u16* __restrict__ Po, const float* __restrict__ Pml,
                                                    float* __restrict__ out, int nsplit) {
    const int gr = blockIdx.x * 16 + (threadIdx.x >> 4);
    const int c0 = (threadIdx.x & 15) * 8;
    const int b = gr >> 12, rr = gr & 4095;
    const int t = rr >> 7, row = rr & 127;
    const int ns = min(nsplit, 2 * t + 2);
    const size_t pbase = (size_t)(b * 32 + t) * nsplit;

    float m[8], l[8], w[8];
    float mstar = -1e30f;
#pragma unroll
    for (int s = 0; s < 8; ++s) {
        m[s] = -1e30f; l[s] = 0.f;
        if (s < ns) {
            const float* ml = Pml + (pbase + s) * 256 + row * 2;
            m[s] = ml[0]; l[s] = ml[1];
            mstar = fmaxf(mstar, m[s]);
        }
    }
    float L = 0.f;
#pragma unroll
    for (int s = 0; s < 8; ++s) {
        w[s] = (s < ns) ? __builtin_amdgcn_exp2f(m[s] - mstar) : 0.f;
        L += w[s] * l[s];
    }
    const float inv = 1.0f / L;

    float acc[8];
#pragma unroll
    for (int k = 0; k < 8; ++k) acc[k] = 0.f;
#pragma unroll
    for (int s = 0; s < 8; ++s) {
        if (s < ns) {
            u32x4 pv = *reinterpret_cast<const u32x4*>(Po + (pbase + s) * (128 * 128) + (size_t)row * 128 + c0);
#pragma unroll
            for (int k = 0; k < 4; ++k) {
                acc[2 * k + 0] += w[s] * bf2f_lo(pv[k]);
                acc[2 * k + 1] += w[s] * bf2f_hi(pv[k]);
            }
        }
    }
    float* op = out + (size_t)gr * D_OUT + c0;
    float4 v0, v1;
    v0.x = acc[0] * inv; v0.y = acc[1] * inv; v0.z = acc[2] * inv; v0.w = acc[3] * inv;
    v1.x = acc[4] * inv; v1.y = acc[5] * inv; v1.z = acc[6] * inv; v1.w = acc[7] * inv;
    *reinterpret_cast<float4*>(op) = v0;
    *reinterpret_cast<float4*>(op + 4) = v1;
}

extern "C" void kernel_launch(void* const* d_in, const int* in_sizes, int n_in,
                              void* d_out, int out_size, void* d_ws, size_t ws_size,
                              hipStream_t stream) {
    const float* x  = (const float*)d_in[0];
    const float* Wq = (const float*)d_in[1];
    const float* Wk = (const float*)d_in[2];
    const float* Wv = (const float*)d_in[3];
    float* out = (float*)d_out;

    // ws layout (u16): Q | K | V^T | W^T | Po | Pml
    u16* Qb = (u16*)d_ws;
    u16* Kb = Qb + (size_t)M_TOTAL * D_OUT;
    u16* Vt = Kb + (size_t)M_TOTAL * D_OUT;
    u16* Wt = Vt + (size_t)M_TOTAL * D_OUT;

    const unsigned long long base = (3ULL * M_TOTAL * D_OUT + 3ULL * D_OUT * D_IN) * 2ULL;
    const unsigned long long per = 4325376ULL; // per-split partials (Po + Pml)
    int nsplit = 8;
    if (ws_size < base + 8ULL * per) nsplit = 4;
    if (ws_size < base + 4ULL * per) nsplit = 2;
    if (ws_size < base + 2ULL * per) nsplit = 1;

    u16* Po = Wt + (size_t)3 * D_OUT * D_IN;
    float* Pml = (float*)(Po + (size_t)nsplit * 128 * 128 * 128);

    wt_kernel<<<72, 256, 0, stream>>>(Wq, Wk, Wv, Wt);
    qkv_kernel<<<dim3(256, 2), 256, 0, stream>>>(x, Wt, Qb, Kb, Vt);
    attn_kernel<<<dim3(32 * nsplit, NB), 256, 0, stream>>>(Qb, Kb, Vt, Po, Pml, out, nsplit);
    if (nsplit > 1)
        merge_kernel<<<M_TOTAL / 16, 256, 0, stream>>>(Po, Pml, out, nsplit);
}